// Round 1
// baseline (2245.407 us; speedup 1.0000x reference)
//
#include <hip/hip_runtime.h>
#include <hip/hip_bf16.h>

#define NQL 900
#define CDIM 256
#define BDIM 8
#define LVTOT 21760

// ---------------- elementwise add (float4) ----------------
__global__ __launch_bounds__(256) void add_kernel(const float4* __restrict__ a,
                                                  const float4* __restrict__ b,
                                                  float4* __restrict__ o, int n4) {
  int i = blockIdx.x * 256 + threadIdx.x;
  if (i < n4) {
    float4 x = a[i], y = b[i];
    o[i] = make_float4(x.x + y.x, x.y + y.y, x.z + y.z, x.w + y.w);
  }
}

// ---------------- generic GEMM: C = A @ W^T + bias (+res) (+relu) ----------------
// A: M x K row-major, W: N x K row-major, C: M x N
template <bool RELU, bool HASRES, bool OUTBF16>
__global__ __launch_bounds__(256) void gemm_kernel(const float* __restrict__ A,
                                                   const float* __restrict__ W,
                                                   const float* __restrict__ bias,
                                                   const float* __restrict__ Rres,
                                                   void* __restrict__ Cout,
                                                   int M, int N, int K) {
  __shared__ __align__(16) float As[16][68];
  __shared__ __align__(16) float Bs[16][68];
  const int tid = threadIdx.x;
  const int tx = tid & 15, ty = tid >> 4;
  const int m0 = blockIdx.y * 64, n0 = blockIdx.x * 64;
  const int lm = tid >> 2, lk = (tid & 3) << 2;
  float acc[4][4] = {};
  for (int k0 = 0; k0 < K; k0 += 16) {
    float4 av = make_float4(0.f, 0.f, 0.f, 0.f);
    int gm = m0 + lm;
    if (gm < M) av = *(const float4*)(A + (size_t)gm * K + k0 + lk);
    float4 wv = make_float4(0.f, 0.f, 0.f, 0.f);
    int gn = n0 + lm;
    if (gn < N) wv = *(const float4*)(W + (size_t)gn * K + k0 + lk);
    As[lk + 0][lm] = av.x; As[lk + 1][lm] = av.y; As[lk + 2][lm] = av.z; As[lk + 3][lm] = av.w;
    Bs[lk + 0][lm] = wv.x; Bs[lk + 1][lm] = wv.y; Bs[lk + 2][lm] = wv.z; Bs[lk + 3][lm] = wv.w;
    __syncthreads();
#pragma unroll
    for (int kk = 0; kk < 16; ++kk) {
      float4 a = *(const float4*)&As[kk][ty << 2];
      float4 bv = *(const float4*)&Bs[kk][tx << 2];
      float af[4] = {a.x, a.y, a.z, a.w};
      float bf[4] = {bv.x, bv.y, bv.z, bv.w};
#pragma unroll
      for (int i = 0; i < 4; ++i)
#pragma unroll
        for (int j = 0; j < 4; ++j) acc[i][j] = fmaf(af[i], bf[j], acc[i][j]);
    }
    __syncthreads();
  }
#pragma unroll
  for (int i = 0; i < 4; ++i) {
    int gm = m0 + (ty << 2) + i;
    if (gm >= M) continue;
#pragma unroll
    for (int j = 0; j < 4; ++j) {
      int gn = n0 + (tx << 2) + j;
      if (gn >= N) continue;
      float v = acc[i][j] + bias[gn];
      if (HASRES) v += Rres[(size_t)gm * N + gn];
      if (RELU) v = fmaxf(v, 0.f);
      if (OUTBF16)
        ((__hip_bfloat16*)Cout)[(size_t)gm * N + gn] = __float2bfloat16(v);
      else
        ((float*)Cout)[(size_t)gm * N + gn] = v;
    }
  }
}

// ---------------- reshape (M x 512 | M x 256) -> qkv[s][b][h][q][d], scale q ----------------
__global__ __launch_bounds__(256) void reshape_qkv_kernel(const float* __restrict__ tmp_qk,
                                                          const float* __restrict__ tmp_v,
                                                          float* __restrict__ qkv) {
  size_t i = (size_t)blockIdx.x * 256 + threadIdx.x;
  const size_t total = (size_t)3 * BDIM * 8 * NQL * 32;
  if (i >= total) return;
  int d = i & 31;
  size_t t = i >> 5;
  int q = t % NQL; t /= NQL;
  int h = t & 7; t >>= 3;
  int b = t & 7;
  int s = t >> 3;
  int c = h * 32 + d;
  size_t row = (size_t)b * NQL + q;
  float v;
  if (s < 2) v = tmp_qk[row * 512 + s * 256 + c];
  else       v = tmp_v[row * 256 + c];
  if (s == 0) v *= 0.17677669529663689f;  // 1/sqrt(32)
  qkv[i] = v;
}

// ---------------- self-attention: one block per (b,h,q) ----------------
__global__ __launch_bounds__(256) void attn_kernel(const float* __restrict__ qkv,
                                                   float* __restrict__ out) {
  const size_t hstr = (size_t)NQL * 32;
  const size_t bstr = 8 * hstr;
  const size_t sstr = 8 * bstr;
  int q = blockIdx.x % NQL;
  int bh = blockIdx.x / NQL;
  int h = bh & 7, b = bh >> 3;
  const float* Qp = qkv + b * bstr + h * hstr + (size_t)q * 32;
  const float* Kp = qkv + sstr + b * bstr + h * hstr;
  const float* Vp = qkv + 2 * sstr + b * bstr + h * hstr;
  __shared__ float qs[32];
  __shared__ float red[256];
  __shared__ float accs[256 * 33];
  int tid = threadIdx.x;
  if (tid < 32) qs[tid] = Qp[tid];
  __syncthreads();
  float sc[4];
  int nk = 0;
  float mx = -1e30f;
  for (int k = tid; k < NQL; k += 256) {
    const float* kp = Kp + (size_t)k * 32;
    float s = 0.f;
#pragma unroll
    for (int d = 0; d < 32; ++d) s = fmaf(qs[d], kp[d], s);
    sc[nk++] = s;
    mx = fmaxf(mx, s);
  }
  red[tid] = mx;
  __syncthreads();
  for (int st = 128; st > 0; st >>= 1) {
    if (tid < st) red[tid] = fmaxf(red[tid], red[tid + st]);
    __syncthreads();
  }
  float bmax = red[0];
  __syncthreads();
  float acc[32];
#pragma unroll
  for (int d = 0; d < 32; ++d) acc[d] = 0.f;
  float lsum = 0.f;
  nk = 0;
  for (int k = tid; k < NQL; k += 256) {
    float p = expf(sc[nk++] - bmax);
    lsum += p;
    const float* vp = Vp + (size_t)k * 32;
#pragma unroll
    for (int d = 0; d < 32; ++d) acc[d] = fmaf(p, vp[d], acc[d]);
  }
  red[tid] = lsum;
  __syncthreads();
  for (int st = 128; st > 0; st >>= 1) {
    if (tid < st) red[tid] += red[tid + st];
    __syncthreads();
  }
  float bsum = red[0];
  float* arow = accs + tid * 33;
#pragma unroll
  for (int d = 0; d < 32; ++d) arow[d] = acc[d];
  __syncthreads();
  for (int st = 128; st > 0; st >>= 1) {
    if (tid < st) {
      float* o = accs + tid * 33;
      const float* p2 = accs + (tid + st) * 33;
#pragma unroll
      for (int d = 0; d < 32; ++d) o[d] += p2[d];
    }
    __syncthreads();
  }
  if (tid < 32)
    out[((size_t)b * NQL + q) * 256 + h * 32 + tid] = accs[tid] / bsum;
}

// ---------------- LayerNorm over 256 ----------------
__global__ __launch_bounds__(256) void ln_kernel(const float* __restrict__ x,
                                                 const float* __restrict__ s,
                                                 const float* __restrict__ bb,
                                                 float* __restrict__ out) {
  int row = blockIdx.x, tid = threadIdx.x;
  float v = x[(size_t)row * 256 + tid];
  __shared__ float r1[256], r2[256];
  r1[tid] = v;
  r2[tid] = v * v;
  __syncthreads();
  for (int st = 128; st > 0; st >>= 1) {
    if (tid < st) { r1[tid] += r1[tid + st]; r2[tid] += r2[tid + st]; }
    __syncthreads();
  }
  float m = r1[0] * (1.f / 256);
  float var = r2[0] * (1.f / 256) - m * m;
  out[(size_t)row * 256 + tid] = (v - m) * rsqrtf(var + 1e-5f) * s[tid] + bb[tid];
}

// ---------------- aw softmax over groups of 16 ----------------
__global__ __launch_bounds__(128) void awsm_kernel(float* __restrict__ aw) {
  int row = blockIdx.x, tid = threadIdx.x;
  float v = aw[(size_t)row * 128 + tid];
  float m = v;
  for (int d = 1; d < 16; d <<= 1) m = fmaxf(m, __shfl_xor(m, d));
  float e = expf(v - m);
  float ssum = e;
  for (int d = 1; d < 16; d <<= 1) ssum += __shfl_xor(ssum, d);
  aw[(size_t)row * 128 + tid] = e / ssum;
}

// ---------------- deformable sampling: block per (b,q), thread = (h,d) ----------------
__global__ __launch_bounds__(256) void deform_kernel(const __hip_bfloat16* __restrict__ value,
                                                     const float* __restrict__ offb,
                                                     const float* __restrict__ awb,
                                                     const float* __restrict__ refp,
                                                     float* __restrict__ dfout) {
  const int Hs[4] = {128, 64, 32, 16};
  const int Stl[4] = {0, 16384, 20480, 21504};
  int row = blockIdx.x;  // b*900+q
  int b = row / NQL;
  int tid = threadIdx.x;
  int h = tid >> 5, d = tid & 31;
  const float* off = offb + (size_t)row * 256;
  const float* aw = awb + (size_t)row * 128;
  const float* ref = refp + (size_t)row * 8;
  const __hip_bfloat16* vb = value + (size_t)b * LVTOT * 256 + h * 32 + d;
  float acc = 0.f;
#pragma unroll
  for (int l = 0; l < 4; ++l) {
    int Wi = Hs[l], Hi = Hs[l];
    float Wl = (float)Wi, Hl = (float)Hi;
    int st = Stl[l];
    float rx = ref[l * 2 + 0], ry = ref[l * 2 + 1];
#pragma unroll
    for (int p = 0; p < 4; ++p) {
      int oi = ((h * 4 + l) * 4 + p) * 2;
      float x = (rx + off[oi] / Wl) * Wl - 0.5f;
      float y = (ry + off[oi + 1] / Hl) * Hl - 0.5f;
      float w = aw[h * 16 + l * 4 + p];
      float x0f = floorf(x), y0f = floorf(y);
      float wx = x - x0f, wy = y - y0f;
      int xi0 = (int)x0f, yi0 = (int)y0f;
      float samp = 0.f;
#pragma unroll
      for (int dy = 0; dy < 2; ++dy) {
#pragma unroll
        for (int dx = 0; dx < 2; ++dx) {
          int xi = xi0 + dx, yi = yi0 + dy;
          float tw = (dx ? wx : 1.f - wx) * (dy ? wy : 1.f - wy);
          bool valid = (xi >= 0) && (xi < Wi) && (yi >= 0) && (yi < Hi);
          int xc = min(max(xi, 0), Wi - 1);
          int yc = min(max(yi, 0), Hi - 1);
          float vv = __bfloat162float(vb[(size_t)(st + yc * Wi + xc) * 256]);
          samp += valid ? tw * vv : 0.f;
        }
      }
      acc = fmaf(w, samp, acc);
    }
  }
  dfout[(size_t)row * 256 + tid] = acc;
}

extern "C" void kernel_launch(void* const* d_in, const int* in_sizes, int n_in,
                              void* d_out, int out_size, void* d_ws, size_t ws_size,
                              hipStream_t stream) {
  const float* tgt = (const float*)d_in[0];
  const float* memory = (const float*)d_in[1];
  const float* qpos = (const float*)d_in[2];
  const float* refp = (const float*)d_in[3];
  const float* sa_in_w = (const float*)d_in[4];
  const float* sa_in_b = (const float*)d_in[5];
  const float* sa_out_w = (const float*)d_in[6];
  const float* sa_out_b = (const float*)d_in[7];
  const float* off_w = (const float*)d_in[8];
  const float* off_b = (const float*)d_in[9];
  const float* aw_w = (const float*)d_in[10];
  const float* aw_b = (const float*)d_in[11];
  const float* val_w = (const float*)d_in[12];
  const float* val_b = (const float*)d_in[13];
  const float* co_w = (const float*)d_in[14];
  const float* co_b = (const float*)d_in[15];
  const float* l1_w = (const float*)d_in[16];
  const float* l1_b = (const float*)d_in[17];
  const float* l2_w = (const float*)d_in[18];
  const float* l2_b = (const float*)d_in[19];
  const float* ln1_s = (const float*)d_in[20];
  const float* ln1_b = (const float*)d_in[21];
  const float* ln2_s = (const float*)d_in[22];
  const float* ln2_b = (const float*)d_in[23];
  const float* ln3_s = (const float*)d_in[24];
  const float* ln3_b = (const float*)d_in[25];

  float* ws = (float*)d_ws;
  const size_t E = (size_t)BDIM * NQL * CDIM;  // 1,843,200
  // phase SA
  float* q_add = ws;            // [0,E)
  float* qkv = ws + E;          // [E,4E)
  float* attn_o = ws + 4 * E;   // [4E,5E)
  float* tmp_qk = ws + 5 * E;   // [5E,7E)
  float* tmp_v = ws + 7 * E;    // [7E,8E)
  float* sa_out = ws + 5 * E;   // reuse tmp_qk after reshape
  // phase deform (SA scratch dead)
  float* q2 = ws;               // [0,E)
  float* offb = ws + E;         // [E,2E)
  float* awb = ws + 2 * E;      // [2E,2.5E)
  float* dfout = ws + 3 * E;    // [3E,4E)
  float* co_out = ws + 4 * E;   // [4E,5E)
  // phase FFN (deform scratch dead)
  float* hidden = ws;           // [0,8E)
  // persistent
  float* tgt1 = ws + 8 * E;
  float* tgt2 = ws + 9 * E;
  float* ffn_o = ws + 10 * E;
  __hip_bfloat16* valbf = (__hip_bfloat16*)(ws + 11 * E);  // 44.56M bf16

  const int M = BDIM * NQL;  // 7200
  const int MG = (M + 63) / 64;
  dim3 blk(256);

  // 1) q = tgt + query_pos
  add_kernel<<<(int)(E / 4 / 256), 256, 0, stream>>>((const float4*)tgt, (const float4*)qpos,
                                                     (float4*)q_add, (int)(E / 4));
  // 2) q,k projections (W rows [0,512))
  gemm_kernel<false, false, false><<<dim3(8, MG), blk, 0, stream>>>(
      q_add, sa_in_w, sa_in_b, nullptr, tmp_qk, M, 512, 256);
  // 3) v projection (W rows [512,768)), input = tgt
  gemm_kernel<false, false, false><<<dim3(4, MG), blk, 0, stream>>>(
      tgt, sa_in_w + 512 * 256, sa_in_b + 512, nullptr, tmp_v, M, 256, 256);
  // 4) reshape to [s][b][h][q][d], scale q by 1/sqrt(32)
  reshape_qkv_kernel<<<(int)((3 * E + 255) / 256), blk, 0, stream>>>(tmp_qk, tmp_v, qkv);
  // 5) attention
  attn_kernel<<<BDIM * 8 * NQL, blk, 0, stream>>>(qkv, attn_o);
  // 6) out projection + residual(tgt)
  gemm_kernel<false, true, false><<<dim3(4, MG), blk, 0, stream>>>(
      attn_o, sa_out_w, sa_out_b, tgt, sa_out, M, 256, 256);
  // 7) LN1 -> tgt1
  ln_kernel<<<M, blk, 0, stream>>>(sa_out, ln1_s, ln1_b, tgt1);
  // 8) q2 = tgt1 + query_pos
  add_kernel<<<(int)(E / 4 / 256), 256, 0, stream>>>((const float4*)tgt1, (const float4*)qpos,
                                                     (float4*)q2, (int)(E / 4));
  // 9) value projection -> bf16 (B*LV x 256)
  gemm_kernel<false, false, true><<<dim3(4, (BDIM * LVTOT) / 64), blk, 0, stream>>>(
      memory, val_w, val_b, nullptr, valbf, BDIM * LVTOT, 256, 256);
  // 10) offsets projection
  gemm_kernel<false, false, false><<<dim3(4, MG), blk, 0, stream>>>(
      q2, off_w, off_b, nullptr, offb, M, 256, 256);
  // 11) attention-weights projection
  gemm_kernel<false, false, false><<<dim3(2, MG), blk, 0, stream>>>(
      q2, aw_w, aw_b, nullptr, awb, M, 128, 256);
  // 12) aw softmax (over 16 per head)
  awsm_kernel<<<M, 128, 0, stream>>>(awb);
  // 13) deformable sampling -> dfout
  deform_kernel<<<M, blk, 0, stream>>>(valbf, offb, awb, refp, dfout);
  // 14) co projection + residual(tgt1)
  gemm_kernel<false, true, false><<<dim3(4, MG), blk, 0, stream>>>(
      dfout, co_w, co_b, tgt1, co_out, M, 256, 256);
  // 15) LN2 -> tgt2
  ln_kernel<<<M, blk, 0, stream>>>(co_out, ln2_s, ln2_b, tgt2);
  // 16) FFN1 + ReLU
  gemm_kernel<true, false, false><<<dim3(32, MG), blk, 0, stream>>>(
      tgt2, l1_w, l1_b, nullptr, hidden, M, 2048, 256);
  // 17) FFN2 + residual(tgt2)
  gemm_kernel<false, true, false><<<dim3(4, MG), blk, 0, stream>>>(
      hidden, l2_w, l2_b, tgt2, ffn_o, M, 256, 2048);
  // 18) LN3 -> out
  ln_kernel<<<M, blk, 0, stream>>>(ffn_o, ln3_s, ln3_b, (float*)d_out);
}

// Round 2
// 1071.791 us; speedup vs baseline: 2.0950x; 2.0950x over previous
//
#include <hip/hip_runtime.h>
#include <hip/hip_bf16.h>

#define NQL 900
#define CDIM 256
#define BDIM 8
#define LVTOT 21760

// ---------------- elementwise add (float4) ----------------
__global__ __launch_bounds__(256) void add_kernel(const float4* __restrict__ a,
                                                  const float4* __restrict__ b,
                                                  float4* __restrict__ o, int n4) {
  int i = blockIdx.x * 256 + threadIdx.x;
  if (i < n4) {
    float4 x = a[i], y = b[i];
    o[i] = make_float4(x.x + y.x, x.y + y.y, x.z + y.z, x.w + y.w);
  }
}

// ---------------- generic GEMM: C = A @ W^T + bias (+res) (+relu) ----------------
template <bool RELU, bool HASRES, bool OUTBF16>
__global__ __launch_bounds__(256) void gemm_kernel(const float* __restrict__ A,
                                                   const float* __restrict__ W,
                                                   const float* __restrict__ bias,
                                                   const float* __restrict__ Rres,
                                                   void* __restrict__ Cout,
                                                   int M, int N, int K) {
  __shared__ __align__(16) float As[16][68];
  __shared__ __align__(16) float Bs[16][68];
  const int tid = threadIdx.x;
  const int tx = tid & 15, ty = tid >> 4;
  const int m0 = blockIdx.y * 64, n0 = blockIdx.x * 64;
  const int lm = tid >> 2, lk = (tid & 3) << 2;
  float acc[4][4] = {};
  for (int k0 = 0; k0 < K; k0 += 16) {
    float4 av = make_float4(0.f, 0.f, 0.f, 0.f);
    int gm = m0 + lm;
    if (gm < M) av = *(const float4*)(A + (size_t)gm * K + k0 + lk);
    float4 wv = make_float4(0.f, 0.f, 0.f, 0.f);
    int gn = n0 + lm;
    if (gn < N) wv = *(const float4*)(W + (size_t)gn * K + k0 + lk);
    As[lk + 0][lm] = av.x; As[lk + 1][lm] = av.y; As[lk + 2][lm] = av.z; As[lk + 3][lm] = av.w;
    Bs[lk + 0][lm] = wv.x; Bs[lk + 1][lm] = wv.y; Bs[lk + 2][lm] = wv.z; Bs[lk + 3][lm] = wv.w;
    __syncthreads();
#pragma unroll
    for (int kk = 0; kk < 16; ++kk) {
      float4 a = *(const float4*)&As[kk][ty << 2];
      float4 bv = *(const float4*)&Bs[kk][tx << 2];
      float af[4] = {a.x, a.y, a.z, a.w};
      float bf[4] = {bv.x, bv.y, bv.z, bv.w};
#pragma unroll
      for (int i = 0; i < 4; ++i)
#pragma unroll
        for (int j = 0; j < 4; ++j) acc[i][j] = fmaf(af[i], bf[j], acc[i][j]);
    }
    __syncthreads();
  }
#pragma unroll
  for (int i = 0; i < 4; ++i) {
    int gm = m0 + (ty << 2) + i;
    if (gm >= M) continue;
#pragma unroll
    for (int j = 0; j < 4; ++j) {
      int gn = n0 + (tx << 2) + j;
      if (gn >= N) continue;
      float v = acc[i][j] + bias[gn];
      if (HASRES) v += Rres[(size_t)gm * N + gn];
      if (RELU) v = fmaxf(v, 0.f);
      if (OUTBF16)
        ((__hip_bfloat16*)Cout)[(size_t)gm * N + gn] = __float2bfloat16(v);
      else
        ((float*)Cout)[(size_t)gm * N + gn] = v;
    }
  }
}

// ---------------- reshape (M x 512 | M x 256) -> qkv[s][b][h][q][d], scale q ----------------
__global__ __launch_bounds__(256) void reshape_qkv_kernel(const float* __restrict__ tmp_qk,
                                                          const float* __restrict__ tmp_v,
                                                          float* __restrict__ qkv) {
  size_t i = (size_t)blockIdx.x * 256 + threadIdx.x;
  const size_t total = (size_t)3 * BDIM * 8 * NQL * 32;
  if (i >= total) return;
  int d = i & 31;
  size_t t = i >> 5;
  int q = t % NQL; t /= NQL;
  int h = t & 7; t >>= 3;
  int b = t & 7;
  int s = t >> 3;
  int c = h * 32 + d;
  size_t row = (size_t)b * NQL + q;
  float v;
  if (s < 2) v = tmp_qk[row * 512 + s * 256 + c];
  else       v = tmp_v[row * 256 + c];
  if (s == 0) v *= 0.17677669529663689f;  // 1/sqrt(32)
  qkv[i] = v;
}

// ---------------- flash self-attention: block = (b,h) x 64-query tile ----------------
// 256 threads: qa = tid>>3 (queries qa, qa+32), kg = tid&7 (keys kg*8..kg*8+7 of tile)
__global__ __launch_bounds__(256, 2) void fattn_kernel(const float* __restrict__ qkv,
                                                       float* __restrict__ out) {
  const size_t hstr = (size_t)NQL * 32;
  const size_t bstr = 8 * hstr;
  const size_t sstr = 8 * bstr;
  const int qt = blockIdx.x;  // 0..14
  const int bh = blockIdx.y;  // 0..63
  const int h = bh & 7, b = bh >> 3;
  const float* Qb = qkv + b * bstr + h * hstr;
  const float* Kb = qkv + sstr + b * bstr + h * hstr;
  const float* Vb = qkv + 2 * sstr + b * bstr + h * hstr;
  const int q0 = qt * 64;

  __shared__ float Ks[64][33];
  __shared__ float Vs[64][33];

  const int tid = threadIdx.x;
  const int sr = tid >> 2;          // staging row 0..63
  const int scl = (tid & 3) << 3;   // staging col 0/8/16/24
  const int qa = tid >> 3;          // 0..31
  const int kg = tid & 7;           // 0..7

  // stage Q tile into Ks, then to registers
  {
    const float* src = Qb + (size_t)min(q0 + sr, NQL - 1) * 32 + scl;
    float4 v0 = *(const float4*)src;
    float4 v1 = *(const float4*)(src + 4);
    float* dst = &Ks[sr][scl];
    dst[0] = v0.x; dst[1] = v0.y; dst[2] = v0.z; dst[3] = v0.w;
    dst[4] = v1.x; dst[5] = v1.y; dst[6] = v1.z; dst[7] = v1.w;
  }
  __syncthreads();
  float qr0[32], qr1[32];
#pragma unroll
  for (int d = 0; d < 32; ++d) { qr0[d] = Ks[qa][d]; qr1[d] = Ks[qa + 32][d]; }

  float m0 = -1e30f, m1 = -1e30f, l0 = 0.f, l1 = 0.f;
  float acc0[32] = {}, acc1[32] = {};

  for (int kt = 0; kt < 15; ++kt) {
    const int k0 = kt * 64;
    __syncthreads();
    {
      const size_t srow = (size_t)min(k0 + sr, NQL - 1) * 32 + scl;
      float4 a0 = *(const float4*)(Kb + srow);
      float4 a1 = *(const float4*)(Kb + srow + 4);
      float4 b0 = *(const float4*)(Vb + srow);
      float4 b1 = *(const float4*)(Vb + srow + 4);
      float* kd = &Ks[sr][scl];
      kd[0] = a0.x; kd[1] = a0.y; kd[2] = a0.z; kd[3] = a0.w;
      kd[4] = a1.x; kd[5] = a1.y; kd[6] = a1.z; kd[7] = a1.w;
      float* vd = &Vs[sr][scl];
      vd[0] = b0.x; vd[1] = b0.y; vd[2] = b0.z; vd[3] = b0.w;
      vd[4] = b1.x; vd[5] = b1.y; vd[6] = b1.z; vd[7] = b1.w;
    }
    __syncthreads();

    float s0[8], s1[8];
    float lm0 = -1e30f, lm1 = -1e30f;
#pragma unroll
    for (int j = 0; j < 8; ++j) {
      const float* kp = &Ks[kg * 8 + j][0];
      float a = 0.f, c = 0.f;
#pragma unroll
      for (int d = 0; d < 32; ++d) {
        float kv = kp[d];
        a = fmaf(qr0[d], kv, a);
        c = fmaf(qr1[d], kv, c);
      }
      bool valid = (k0 + kg * 8 + j) < NQL;
      a = valid ? a : -1e30f;
      c = valid ? c : -1e30f;
      s0[j] = a; s1[j] = c;
      lm0 = fmaxf(lm0, a); lm1 = fmaxf(lm1, c);
    }
#pragma unroll
    for (int w = 1; w < 8; w <<= 1) {
      lm0 = fmaxf(lm0, __shfl_xor(lm0, w));
      lm1 = fmaxf(lm1, __shfl_xor(lm1, w));
    }
    float mn0 = fmaxf(m0, lm0), mn1 = fmaxf(m1, lm1);
    float rs0 = __expf(m0 - mn0), rs1 = __expf(m1 - mn1);
    float ls0 = 0.f, ls1 = 0.f;
#pragma unroll
    for (int j = 0; j < 8; ++j) {
      float p0 = __expf(s0[j] - mn0);
      float p1 = __expf(s1[j] - mn1);
      s0[j] = p0; s1[j] = p1;
      ls0 += p0; ls1 += p1;
    }
#pragma unroll
    for (int w = 1; w < 8; w <<= 1) { ls0 += __shfl_xor(ls0, w); ls1 += __shfl_xor(ls1, w); }
    l0 = l0 * rs0 + ls0; l1 = l1 * rs1 + ls1;
    m0 = mn0; m1 = mn1;
#pragma unroll
    for (int d = 0; d < 32; ++d) { acc0[d] *= rs0; acc1[d] *= rs1; }
#pragma unroll
    for (int j = 0; j < 8; ++j) {
      const float* vp = &Vs[kg * 8 + j][0];
      float p0 = s0[j], p1 = s1[j];
#pragma unroll
      for (int d = 0; d < 32; ++d) {
        float vv = vp[d];
        acc0[d] = fmaf(p0, vv, acc0[d]);
        acc1[d] = fmaf(p1, vv, acc1[d]);
      }
    }
  }
  // reduce partial O across the 8 kg lanes (same wave: lanes qa*8+kg)
#pragma unroll
  for (int w = 1; w < 8; w <<= 1) {
#pragma unroll
    for (int d = 0; d < 32; ++d) {
      acc0[d] += __shfl_xor(acc0[d], w);
      acc1[d] += __shfl_xor(acc1[d], w);
    }
  }
  __syncthreads();
  if (kg == 0) {
    float inv0 = 1.f / l0, inv1 = 1.f / l1;
#pragma unroll
    for (int d = 0; d < 32; ++d) {
      Ks[qa][d] = acc0[d] * inv0;
      Ks[qa + 32][d] = acc1[d] * inv1;
    }
  }
  __syncthreads();
  {
    int gq = q0 + sr;
    if (gq < NQL) {
      float* op = out + ((size_t)b * NQL + gq) * 256 + h * 32 + scl;
      float4 o0 = make_float4(Ks[sr][scl + 0], Ks[sr][scl + 1], Ks[sr][scl + 2], Ks[sr][scl + 3]);
      float4 o1 = make_float4(Ks[sr][scl + 4], Ks[sr][scl + 5], Ks[sr][scl + 6], Ks[sr][scl + 7]);
      *(float4*)op = o0;
      *(float4*)(op + 4) = o1;
    }
  }
}

// ---------------- LayerNorm over 256 ----------------
__global__ __launch_bounds__(256) void ln_kernel(const float* __restrict__ x,
                                                 const float* __restrict__ s,
                                                 const float* __restrict__ bb,
                                                 float* __restrict__ out) {
  int row = blockIdx.x, tid = threadIdx.x;
  float v = x[(size_t)row * 256 + tid];
  __shared__ float r1[256], r2[256];
  r1[tid] = v;
  r2[tid] = v * v;
  __syncthreads();
  for (int st = 128; st > 0; st >>= 1) {
    if (tid < st) { r1[tid] += r1[tid + st]; r2[tid] += r2[tid + st]; }
    __syncthreads();
  }
  float m = r1[0] * (1.f / 256);
  float var = r2[0] * (1.f / 256) - m * m;
  out[(size_t)row * 256 + tid] = (v - m) * rsqrtf(var + 1e-5f) * s[tid] + bb[tid];
}

// ---------------- aw softmax over groups of 16 ----------------
__global__ __launch_bounds__(128) void awsm_kernel(float* __restrict__ aw) {
  int row = blockIdx.x, tid = threadIdx.x;
  float v = aw[(size_t)row * 128 + tid];
  float m = v;
  for (int d = 1; d < 16; d <<= 1) m = fmaxf(m, __shfl_xor(m, d));
  float e = expf(v - m);
  float ssum = e;
  for (int d = 1; d < 16; d <<= 1) ssum += __shfl_xor(ssum, d);
  aw[(size_t)row * 128 + tid] = e / ssum;
}

// ---------------- deformable sampling: block per (b,q), thread = (h,d) ----------------
__global__ __launch_bounds__(256) void deform_kernel(const __hip_bfloat16* __restrict__ value,
                                                     const float* __restrict__ offb,
                                                     const float* __restrict__ awb,
                                                     const float* __restrict__ refp,
                                                     float* __restrict__ dfout) {
  const int Hs[4] = {128, 64, 32, 16};
  const int Stl[4] = {0, 16384, 20480, 21504};
  int row = blockIdx.x;  // b*900+q
  int b = row / NQL;
  int tid = threadIdx.x;
  int h = tid >> 5, d = tid & 31;
  const float* off = offb + (size_t)row * 256;
  const float* aw = awb + (size_t)row * 128;
  const float* ref = refp + (size_t)row * 8;
  const __hip_bfloat16* vb = value + (size_t)b * LVTOT * 256 + h * 32 + d;
  float acc = 0.f;
#pragma unroll
  for (int l = 0; l < 4; ++l) {
    int Wi = Hs[l], Hi = Hs[l];
    float Wl = (float)Wi, Hl = (float)Hi;
    int st = Stl[l];
    float rx = ref[l * 2 + 0], ry = ref[l * 2 + 1];
#pragma unroll
    for (int p = 0; p < 4; ++p) {
      int oi = ((h * 4 + l) * 4 + p) * 2;
      float x = (rx + off[oi] / Wl) * Wl - 0.5f;
      float y = (ry + off[oi + 1] / Hl) * Hl - 0.5f;
      float w = aw[h * 16 + l * 4 + p];
      float x0f = floorf(x), y0f = floorf(y);
      float wx = x - x0f, wy = y - y0f;
      int xi0 = (int)x0f, yi0 = (int)y0f;
      float samp = 0.f;
#pragma unroll
      for (int dy = 0; dy < 2; ++dy) {
#pragma unroll
        for (int dx = 0; dx < 2; ++dx) {
          int xi = xi0 + dx, yi = yi0 + dy;
          float tw = (dx ? wx : 1.f - wx) * (dy ? wy : 1.f - wy);
          bool valid = (xi >= 0) && (xi < Wi) && (yi >= 0) && (yi < Hi);
          int xc = min(max(xi, 0), Wi - 1);
          int yc = min(max(yi, 0), Hi - 1);
          float vv = __bfloat162float(vb[(size_t)(st + yc * Wi + xc) * 256]);
          samp += valid ? tw * vv : 0.f;
        }
      }
      acc = fmaf(w, samp, acc);
    }
  }
  dfout[(size_t)row * 256 + tid] = acc;
}

extern "C" void kernel_launch(void* const* d_in, const int* in_sizes, int n_in,
                              void* d_out, int out_size, void* d_ws, size_t ws_size,
                              hipStream_t stream) {
  const float* tgt = (const float*)d_in[0];
  const float* memory = (const float*)d_in[1];
  const float* qpos = (const float*)d_in[2];
  const float* refp = (const float*)d_in[3];
  const float* sa_in_w = (const float*)d_in[4];
  const float* sa_in_b = (const float*)d_in[5];
  const float* sa_out_w = (const float*)d_in[6];
  const float* sa_out_b = (const float*)d_in[7];
  const float* off_w = (const float*)d_in[8];
  const float* off_b = (const float*)d_in[9];
  const float* aw_w = (const float*)d_in[10];
  const float* aw_b = (const float*)d_in[11];
  const float* val_w = (const float*)d_in[12];
  const float* val_b = (const float*)d_in[13];
  const float* co_w = (const float*)d_in[14];
  const float* co_b = (const float*)d_in[15];
  const float* l1_w = (const float*)d_in[16];
  const float* l1_b = (const float*)d_in[17];
  const float* l2_w = (const float*)d_in[18];
  const float* l2_b = (const float*)d_in[19];
  const float* ln1_s = (const float*)d_in[20];
  const float* ln1_b = (const float*)d_in[21];
  const float* ln2_s = (const float*)d_in[22];
  const float* ln2_b = (const float*)d_in[23];
  const float* ln3_s = (const float*)d_in[24];
  const float* ln3_b = (const float*)d_in[25];

  float* ws = (float*)d_ws;
  const size_t E = (size_t)BDIM * NQL * CDIM;  // 1,843,200
  // phase SA
  float* q_add = ws;            // [0,E)
  float* qkv = ws + E;          // [E,4E)
  float* attn_o = ws + 4 * E;   // [4E,5E)
  float* tmp_qk = ws + 5 * E;   // [5E,7E)
  float* tmp_v = ws + 7 * E;    // [7E,8E)
  float* sa_out = ws + 5 * E;   // reuse tmp_qk after reshape
  // phase deform (SA scratch dead)
  float* q2 = ws;               // [0,E)
  float* offb = ws + E;         // [E,2E)
  float* awb = ws + 2 * E;      // [2E,2.5E)
  float* dfout = ws + 3 * E;    // [3E,4E)
  float* co_out = ws + 4 * E;   // [4E,5E)
  // phase FFN (deform scratch dead)
  float* hidden = ws;           // [0,8E)
  // persistent
  float* tgt1 = ws + 8 * E;
  float* tgt2 = ws + 9 * E;
  float* ffn_o = ws + 10 * E;
  __hip_bfloat16* valbf = (__hip_bfloat16*)(ws + 11 * E);

  const int M = BDIM * NQL;  // 7200
  const int MG = (M + 63) / 64;
  dim3 blk(256);

  // 1) q = tgt + query_pos
  add_kernel<<<(int)(E / 4 / 256), 256, 0, stream>>>((const float4*)tgt, (const float4*)qpos,
                                                     (float4*)q_add, (int)(E / 4));
  // 2) q,k projections (W rows [0,512))
  gemm_kernel<false, false, false><<<dim3(8, MG), blk, 0, stream>>>(
      q_add, sa_in_w, sa_in_b, nullptr, tmp_qk, M, 512, 256);
  // 3) v projection (W rows [512,768)), input = tgt
  gemm_kernel<false, false, false><<<dim3(4, MG), blk, 0, stream>>>(
      tgt, sa_in_w + 512 * 256, sa_in_b + 512, nullptr, tmp_v, M, 256, 256);
  // 4) reshape to [s][b][h][q][d], scale q by 1/sqrt(32)
  reshape_qkv_kernel<<<(int)((3 * E + 255) / 256), blk, 0, stream>>>(tmp_qk, tmp_v, qkv);
  // 5) flash attention
  fattn_kernel<<<dim3(15, 64), blk, 0, stream>>>(qkv, attn_o);
  // 6) out projection + residual(tgt)
  gemm_kernel<false, true, false><<<dim3(4, MG), blk, 0, stream>>>(
      attn_o, sa_out_w, sa_out_b, tgt, sa_out, M, 256, 256);
  // 7) LN1 -> tgt1
  ln_kernel<<<M, blk, 0, stream>>>(sa_out, ln1_s, ln1_b, tgt1);
  // 8) q2 = tgt1 + query_pos
  add_kernel<<<(int)(E / 4 / 256), 256, 0, stream>>>((const float4*)tgt1, (const float4*)qpos,
                                                     (float4*)q2, (int)(E / 4));
  // 9) value projection -> bf16 (B*LV x 256)
  gemm_kernel<false, false, true><<<dim3(4, (BDIM * LVTOT) / 64), blk, 0, stream>>>(
      memory, val_w, val_b, nullptr, valbf, BDIM * LVTOT, 256, 256);
  // 10) offsets projection
  gemm_kernel<false, false, false><<<dim3(4, MG), blk, 0, stream>>>(
      q2, off_w, off_b, nullptr, offb, M, 256, 256);
  // 11) attention-weights projection
  gemm_kernel<false, false, false><<<dim3(2, MG), blk, 0, stream>>>(
      q2, aw_w, aw_b, nullptr, awb, M, 128, 256);
  // 12) aw softmax (over 16 per head)
  awsm_kernel<<<M, 128, 0, stream>>>(awb);
  // 13) deformable sampling -> dfout
  deform_kernel<<<M, blk, 0, stream>>>(valbf, offb, awb, refp, dfout);
  // 14) co projection + residual(tgt1)
  gemm_kernel<false, true, false><<<dim3(4, MG), blk, 0, stream>>>(
      dfout, co_w, co_b, tgt1, co_out, M, 256, 256);
  // 15) LN2 -> tgt2
  ln_kernel<<<M, blk, 0, stream>>>(co_out, ln2_s, ln2_b, tgt2);
  // 16) FFN1 + ReLU
  gemm_kernel<true, false, false><<<dim3(32, MG), blk, 0, stream>>>(
      tgt2, l1_w, l1_b, nullptr, hidden, M, 2048, 256);
  // 17) FFN2 + residual(tgt2)
  gemm_kernel<false, true, false><<<dim3(4, MG), blk, 0, stream>>>(
      hidden, l2_w, l2_b, tgt2, ffn_o, M, 256, 2048);
  // 18) LN3 -> out
  ln_kernel<<<M, blk, 0, stream>>>(ffn_o, ln3_s, ln3_b, (float*)d_out);
}

// Round 3
// 756.923 us; speedup vs baseline: 2.9665x; 1.4160x over previous
//
#include <hip/hip_runtime.h>
#include <hip/hip_bf16.h>

#define NQL 900
#define CDIM 256
#define BDIM 8
#define LVTOT 21760

typedef __bf16 bf16x8 __attribute__((ext_vector_type(8)));
typedef float f32x4 __attribute__((ext_vector_type(4)));
typedef uint u32x4 __attribute__((ext_vector_type(4)));

__device__ __forceinline__ ushort f2bf(float x) {
  uint u = __builtin_bit_cast(uint, x);
  u += 0x7fff + ((u >> 16) & 1);
  return (ushort)(u >> 16);
}

// ---------------- elementwise add (float4) ----------------
__global__ __launch_bounds__(256) void add_kernel(const float4* __restrict__ a,
                                                  const float4* __restrict__ b,
                                                  float4* __restrict__ o, int n4) {
  int i = blockIdx.x * 256 + threadIdx.x;
  if (i < n4) {
    float4 x = a[i], y = b[i];
    o[i] = make_float4(x.x + y.x, x.y + y.y, x.z + y.z, x.w + y.w);
  }
}

// ---------------- bf16 MFMA GEMM: C = A @ W^T + bias (+res)(+relu) ----------------
// A: M x K (fp32 or bf16 per ABF16), W: N x K fp32 (converted inline), C: M x N.
// BM=BN=128, BK=32, 4 waves of 64x64. Requires N % 128 == 0, K % 32 == 0.
template <bool ABF16, bool RELU, bool HASRES, bool OUTBF16>
__global__ __launch_bounds__(256, 2) void mgemm_kernel(const void* __restrict__ Ap,
                                                       const float* __restrict__ W,
                                                       const float* __restrict__ bias,
                                                       const float* __restrict__ Rres,
                                                       void* __restrict__ Cout,
                                                       int M, int N, int K) {
  __shared__ ushort As[128 * 40];
  __shared__ ushort Bs[128 * 40];
  const int tid = threadIdx.x;
  const int m0 = blockIdx.y * 128, n0 = blockIdx.x * 128;
  const int wv = tid >> 6;
  const int wm = (wv >> 1) * 64, wn = (wv & 1) * 64;
  const int lane = tid & 63;
  const int lr = lane & 15, kq = lane >> 4;

  f32x4 acc[4][4] = {};

  for (int k0 = 0; k0 < K; k0 += 32) {
#pragma unroll
    for (int it = 0; it < 2; ++it) {
      int idx = it * 256 + tid;
      int r = idx >> 2, s = idx & 3;
      {  // A tile
        int gm = min(m0 + r, M - 1);
        u32x4 u;
        if constexpr (ABF16) {
          u = *(const u32x4*)((const ushort*)Ap + (size_t)gm * K + k0 + s * 8);
        } else {
          const float* ap = (const float*)Ap + (size_t)gm * K + k0 + s * 8;
          float4 f0 = *(const float4*)ap;
          float4 f1 = *(const float4*)(ap + 4);
          u.x = f2bf(f0.x) | ((uint)f2bf(f0.y) << 16);
          u.y = f2bf(f0.z) | ((uint)f2bf(f0.w) << 16);
          u.z = f2bf(f1.x) | ((uint)f2bf(f1.y) << 16);
          u.w = f2bf(f1.z) | ((uint)f2bf(f1.w) << 16);
        }
        *(u32x4*)&As[r * 40 + s * 8] = u;
      }
      {  // B tile (W rows)
        int gn = min(n0 + r, N - 1);
        const float* wp = W + (size_t)gn * K + k0 + s * 8;
        float4 f0 = *(const float4*)wp;
        float4 f1 = *(const float4*)(wp + 4);
        u32x4 u;
        u.x = f2bf(f0.x) | ((uint)f2bf(f0.y) << 16);
        u.y = f2bf(f0.z) | ((uint)f2bf(f0.w) << 16);
        u.z = f2bf(f1.x) | ((uint)f2bf(f1.y) << 16);
        u.w = f2bf(f1.z) | ((uint)f2bf(f1.w) << 16);
        *(u32x4*)&Bs[r * 40 + s * 8] = u;
      }
    }
    __syncthreads();
    bf16x8 af[4], bq[4];
#pragma unroll
    for (int m = 0; m < 4; ++m)
      af[m] = __builtin_bit_cast(bf16x8, *(const u32x4*)&As[(wm + m * 16 + lr) * 40 + kq * 8]);
#pragma unroll
    for (int n = 0; n < 4; ++n)
      bq[n] = __builtin_bit_cast(bf16x8, *(const u32x4*)&Bs[(wn + n * 16 + lr) * 40 + kq * 8]);
#pragma unroll
    for (int m = 0; m < 4; ++m)
#pragma unroll
      for (int n = 0; n < 4; ++n)
        acc[m][n] = __builtin_amdgcn_mfma_f32_16x16x32_bf16(af[m], bq[n], acc[m][n], 0, 0, 0);
    __syncthreads();
  }

#pragma unroll
  for (int n = 0; n < 4; ++n) {
    int gcol = n0 + wn + n * 16 + lr;
    float bv = bias[gcol];
#pragma unroll
    for (int m = 0; m < 4; ++m) {
      int rbase = m0 + wm + m * 16 + kq * 4;
#pragma unroll
      for (int j = 0; j < 4; ++j) {
        int grow = rbase + j;
        if (grow >= M) continue;
        float v = acc[m][n][j] + bv;
        if (HASRES) v += Rres[(size_t)grow * N + gcol];
        if (RELU) v = fmaxf(v, 0.f);
        if (OUTBF16)
          ((ushort*)Cout)[(size_t)grow * N + gcol] = f2bf(v);
        else
          ((float*)Cout)[(size_t)grow * N + gcol] = v;
      }
    }
  }
}

// ---------------- reshape (M x 512 | M x 256) -> qkv[s][b][h][q][d], scale q ----------------
__global__ __launch_bounds__(256) void reshape_qkv_kernel(const float* __restrict__ tmp_qk,
                                                          const float* __restrict__ tmp_v,
                                                          float* __restrict__ qkv) {
  size_t i = (size_t)blockIdx.x * 256 + threadIdx.x;
  const size_t total = (size_t)3 * BDIM * 8 * NQL * 32;
  if (i >= total) return;
  int d = i & 31;
  size_t t = i >> 5;
  int q = t % NQL; t /= NQL;
  int h = t & 7; t >>= 3;
  int b = t & 7;
  int s = t >> 3;
  int c = h * 32 + d;
  size_t row = (size_t)b * NQL + q;
  float v;
  if (s < 2) v = tmp_qk[row * 512 + s * 256 + c];
  else       v = tmp_v[row * 256 + c];
  if (s == 0) v *= 0.17677669529663689f;  // 1/sqrt(32)
  qkv[i] = v;
}

// ---------------- flash self-attention: block = (b,h) x 64-query tile ----------------
__global__ __launch_bounds__(256, 2) void fattn_kernel(const float* __restrict__ qkv,
                                                       float* __restrict__ out) {
  const size_t hstr = (size_t)NQL * 32;
  const size_t bstr = 8 * hstr;
  const size_t sstr = 8 * bstr;
  const int qt = blockIdx.x;
  const int bh = blockIdx.y;
  const int h = bh & 7, b = bh >> 3;
  const float* Qb = qkv + b * bstr + h * hstr;
  const float* Kb = qkv + sstr + b * bstr + h * hstr;
  const float* Vb = qkv + 2 * sstr + b * bstr + h * hstr;
  const int q0 = qt * 64;

  __shared__ float Ks[64][33];
  __shared__ float Vs[64][33];

  const int tid = threadIdx.x;
  const int sr = tid >> 2;
  const int scl = (tid & 3) << 3;
  const int qa = tid >> 3;
  const int kg = tid & 7;

  {
    const float* src = Qb + (size_t)min(q0 + sr, NQL - 1) * 32 + scl;
    float4 v0 = *(const float4*)src;
    float4 v1 = *(const float4*)(src + 4);
    float* dst = &Ks[sr][scl];
    dst[0] = v0.x; dst[1] = v0.y; dst[2] = v0.z; dst[3] = v0.w;
    dst[4] = v1.x; dst[5] = v1.y; dst[6] = v1.z; dst[7] = v1.w;
  }
  __syncthreads();
  float qr0[32], qr1[32];
#pragma unroll
  for (int d = 0; d < 32; ++d) { qr0[d] = Ks[qa][d]; qr1[d] = Ks[qa + 32][d]; }

  float m0 = -1e30f, m1 = -1e30f, l0 = 0.f, l1 = 0.f;
  float acc0[32] = {}, acc1[32] = {};

  for (int kt = 0; kt < 15; ++kt) {
    const int k0 = kt * 64;
    __syncthreads();
    {
      const size_t srow = (size_t)min(k0 + sr, NQL - 1) * 32 + scl;
      float4 a0 = *(const float4*)(Kb + srow);
      float4 a1 = *(const float4*)(Kb + srow + 4);
      float4 b0 = *(const float4*)(Vb + srow);
      float4 b1 = *(const float4*)(Vb + srow + 4);
      float* kd = &Ks[sr][scl];
      kd[0] = a0.x; kd[1] = a0.y; kd[2] = a0.z; kd[3] = a0.w;
      kd[4] = a1.x; kd[5] = a1.y; kd[6] = a1.z; kd[7] = a1.w;
      float* vd = &Vs[sr][scl];
      vd[0] = b0.x; vd[1] = b0.y; vd[2] = b0.z; vd[3] = b0.w;
      vd[4] = b1.x; vd[5] = b1.y; vd[6] = b1.z; vd[7] = b1.w;
    }
    __syncthreads();

    float s0[8], s1[8];
    float lm0 = -1e30f, lm1 = -1e30f;
#pragma unroll
    for (int j = 0; j < 8; ++j) {
      const float* kp = &Ks[kg * 8 + j][0];
      float a = 0.f, c = 0.f;
#pragma unroll
      for (int d = 0; d < 32; ++d) {
        float kv = kp[d];
        a = fmaf(qr0[d], kv, a);
        c = fmaf(qr1[d], kv, c);
      }
      bool valid = (k0 + kg * 8 + j) < NQL;
      a = valid ? a : -1e30f;
      c = valid ? c : -1e30f;
      s0[j] = a; s1[j] = c;
      lm0 = fmaxf(lm0, a); lm1 = fmaxf(lm1, c);
    }
#pragma unroll
    for (int w = 1; w < 8; w <<= 1) {
      lm0 = fmaxf(lm0, __shfl_xor(lm0, w));
      lm1 = fmaxf(lm1, __shfl_xor(lm1, w));
    }
    float mn0 = fmaxf(m0, lm0), mn1 = fmaxf(m1, lm1);
    float rs0 = __expf(m0 - mn0), rs1 = __expf(m1 - mn1);
    float ls0 = 0.f, ls1 = 0.f;
#pragma unroll
    for (int j = 0; j < 8; ++j) {
      float p0 = __expf(s0[j] - mn0);
      float p1 = __expf(s1[j] - mn1);
      s0[j] = p0; s1[j] = p1;
      ls0 += p0; ls1 += p1;
    }
#pragma unroll
    for (int w = 1; w < 8; w <<= 1) { ls0 += __shfl_xor(ls0, w); ls1 += __shfl_xor(ls1, w); }
    l0 = l0 * rs0 + ls0; l1 = l1 * rs1 + ls1;
    m0 = mn0; m1 = mn1;
#pragma unroll
    for (int d = 0; d < 32; ++d) { acc0[d] *= rs0; acc1[d] *= rs1; }
#pragma unroll
    for (int j = 0; j < 8; ++j) {
      const float* vp = &Vs[kg * 8 + j][0];
      float p0 = s0[j], p1 = s1[j];
#pragma unroll
      for (int d = 0; d < 32; ++d) {
        float vv = vp[d];
        acc0[d] = fmaf(p0, vv, acc0[d]);
        acc1[d] = fmaf(p1, vv, acc1[d]);
      }
    }
  }
#pragma unroll
  for (int w = 1; w < 8; w <<= 1) {
#pragma unroll
    for (int d = 0; d < 32; ++d) {
      acc0[d] += __shfl_xor(acc0[d], w);
      acc1[d] += __shfl_xor(acc1[d], w);
    }
  }
  __syncthreads();
  if (kg == 0) {
    float inv0 = 1.f / l0, inv1 = 1.f / l1;
#pragma unroll
    for (int d = 0; d < 32; ++d) {
      Ks[qa][d] = acc0[d] * inv0;
      Ks[qa + 32][d] = acc1[d] * inv1;
    }
  }
  __syncthreads();
  {
    int gq = q0 + sr;
    if (gq < NQL) {
      float* op = out + ((size_t)b * NQL + gq) * 256 + h * 32 + scl;
      float4 o0 = make_float4(Ks[sr][scl + 0], Ks[sr][scl + 1], Ks[sr][scl + 2], Ks[sr][scl + 3]);
      float4 o1 = make_float4(Ks[sr][scl + 4], Ks[sr][scl + 5], Ks[sr][scl + 6], Ks[sr][scl + 7]);
      *(float4*)op = o0;
      *(float4*)(op + 4) = o1;
    }
  }
}

// ---------------- LayerNorm over 256 ----------------
__global__ __launch_bounds__(256) void ln_kernel(const float* __restrict__ x,
                                                 const float* __restrict__ s,
                                                 const float* __restrict__ bb,
                                                 float* __restrict__ out) {
  int row = blockIdx.x, tid = threadIdx.x;
  float v = x[(size_t)row * 256 + tid];
  __shared__ float r1[256], r2[256];
  r1[tid] = v;
  r2[tid] = v * v;
  __syncthreads();
  for (int st = 128; st > 0; st >>= 1) {
    if (tid < st) { r1[tid] += r1[tid + st]; r2[tid] += r2[tid + st]; }
    __syncthreads();
  }
  float m = r1[0] * (1.f / 256);
  float var = r2[0] * (1.f / 256) - m * m;
  out[(size_t)row * 256 + tid] = (v - m) * rsqrtf(var + 1e-5f) * s[tid] + bb[tid];
}

// ---------------- aw softmax over groups of 16 ----------------
__global__ __launch_bounds__(128) void awsm_kernel(float* __restrict__ aw) {
  int row = blockIdx.x, tid = threadIdx.x;
  float v = aw[(size_t)row * 128 + tid];
  float m = v;
  for (int d = 1; d < 16; d <<= 1) m = fmaxf(m, __shfl_xor(m, d));
  float e = expf(v - m);
  float ssum = e;
  for (int d = 1; d < 16; d <<= 1) ssum += __shfl_xor(ssum, d);
  aw[(size_t)row * 128 + tid] = e / ssum;
}

// ---------------- deformable sampling: block per (b,q), thread = (h,d) ----------------
__global__ __launch_bounds__(256) void deform_kernel(const __hip_bfloat16* __restrict__ value,
                                                     const float* __restrict__ offb,
                                                     const float* __restrict__ awb,
                                                     const float* __restrict__ refp,
                                                     float* __restrict__ dfout) {
  const int Hs[4] = {128, 64, 32, 16};
  const int Stl[4] = {0, 16384, 20480, 21504};
  int row = blockIdx.x;  // b*900+q
  int b = row / NQL;
  int tid = threadIdx.x;
  int h = tid >> 5, d = tid & 31;
  const float* off = offb + (size_t)row * 256;
  const float* aw = awb + (size_t)row * 128;
  const float* ref = refp + (size_t)row * 8;
  const __hip_bfloat16* vb = value + (size_t)b * LVTOT * 256 + h * 32 + d;
  float acc = 0.f;
#pragma unroll
  for (int l = 0; l < 4; ++l) {
    int Wi = Hs[l], Hi = Hs[l];
    float Wl = (float)Wi, Hl = (float)Hi;
    int st = Stl[l];
    float rx = ref[l * 2 + 0], ry = ref[l * 2 + 1];
#pragma unroll
    for (int p = 0; p < 4; ++p) {
      int oi = ((h * 4 + l) * 4 + p) * 2;
      float x = (rx + off[oi] / Wl) * Wl - 0.5f;
      float y = (ry + off[oi + 1] / Hl) * Hl - 0.5f;
      float w = aw[h * 16 + l * 4 + p];
      float x0f = floorf(x), y0f = floorf(y);
      float wx = x - x0f, wy = y - y0f;
      int xi0 = (int)x0f, yi0 = (int)y0f;
      float samp = 0.f;
#pragma unroll
      for (int dy = 0; dy < 2; ++dy) {
#pragma unroll
        for (int dx = 0; dx < 2; ++dx) {
          int xi = xi0 + dx, yi = yi0 + dy;
          float tw = (dx ? wx : 1.f - wx) * (dy ? wy : 1.f - wy);
          bool valid = (xi >= 0) && (xi < Wi) && (yi >= 0) && (yi < Hi);
          int xc = min(max(xi, 0), Wi - 1);
          int yc = min(max(yi, 0), Hi - 1);
          float vv = __bfloat162float(vb[(size_t)(st + yc * Wi + xc) * 256]);
          samp += valid ? tw * vv : 0.f;
        }
      }
      acc = fmaf(w, samp, acc);
    }
  }
  dfout[(size_t)row * 256 + tid] = acc;
}

extern "C" void kernel_launch(void* const* d_in, const int* in_sizes, int n_in,
                              void* d_out, int out_size, void* d_ws, size_t ws_size,
                              hipStream_t stream) {
  const float* tgt = (const float*)d_in[0];
  const float* memory = (const float*)d_in[1];
  const float* qpos = (const float*)d_in[2];
  const float* refp = (const float*)d_in[3];
  const float* sa_in_w = (const float*)d_in[4];
  const float* sa_in_b = (const float*)d_in[5];
  const float* sa_out_w = (const float*)d_in[6];
  const float* sa_out_b = (const float*)d_in[7];
  const float* off_w = (const float*)d_in[8];
  const float* off_b = (const float*)d_in[9];
  const float* aw_w = (const float*)d_in[10];
  const float* aw_b = (const float*)d_in[11];
  const float* val_w = (const float*)d_in[12];
  const float* val_b = (const float*)d_in[13];
  const float* co_w = (const float*)d_in[14];
  const float* co_b = (const float*)d_in[15];
  const float* l1_w = (const float*)d_in[16];
  const float* l1_b = (const float*)d_in[17];
  const float* l2_w = (const float*)d_in[18];
  const float* l2_b = (const float*)d_in[19];
  const float* ln1_s = (const float*)d_in[20];
  const float* ln1_b = (const float*)d_in[21];
  const float* ln2_s = (const float*)d_in[22];
  const float* ln2_b = (const float*)d_in[23];
  const float* ln3_s = (const float*)d_in[24];
  const float* ln3_b = (const float*)d_in[25];

  float* ws = (float*)d_ws;
  const size_t E = (size_t)BDIM * NQL * CDIM;  // 1,843,200
  // phase SA
  float* q_add = ws;            // [0,E)
  float* qkv = ws + E;          // [E,4E)
  float* attn_o = ws + 4 * E;   // [4E,5E)
  float* tmp_qk = ws + 5 * E;   // [5E,7E)
  float* tmp_v = ws + 7 * E;    // [7E,8E)
  float* sa_out = ws + 5 * E;   // reuse tmp_qk after reshape
  // phase deform (SA scratch dead)
  float* q2 = ws;               // [0,E)
  float* offb = ws + E;         // [E,2E)
  float* awb = ws + 2 * E;      // [2E,2.5E)
  float* dfout = ws + 3 * E;    // [3E,4E)
  float* co_out = ws + 4 * E;   // [4E,5E)
  // phase FFN (deform scratch dead)
  ushort* hidden = (ushort*)ws; // bf16 [7200 x 2048] = 29.5 MB
  // persistent
  float* tgt1 = ws + 8 * E;
  float* tgt2 = ws + 9 * E;
  float* ffn_o = ws + 10 * E;
  ushort* valbf = (ushort*)(ws + 11 * E);  // bf16 [174080 x 256]

  const int M = BDIM * NQL;  // 7200
  const int MT = (M + 127) / 128;  // 57
  dim3 blk(256);

  // 1) q = tgt + query_pos
  add_kernel<<<(int)(E / 4 / 256), 256, 0, stream>>>((const float4*)tgt, (const float4*)qpos,
                                                     (float4*)q_add, (int)(E / 4));
  // 2) q,k projections (W rows [0,512))
  mgemm_kernel<false, false, false, false><<<dim3(4, MT), blk, 0, stream>>>(
      q_add, sa_in_w, sa_in_b, nullptr, tmp_qk, M, 512, 256);
  // 3) v projection (W rows [512,768)), input = tgt
  mgemm_kernel<false, false, false, false><<<dim3(2, MT), blk, 0, stream>>>(
      tgt, sa_in_w + 512 * 256, sa_in_b + 512, nullptr, tmp_v, M, 256, 256);
  // 4) reshape to [s][b][h][q][d], scale q by 1/sqrt(32)
  reshape_qkv_kernel<<<(int)((3 * E + 255) / 256), blk, 0, stream>>>(tmp_qk, tmp_v, qkv);
  // 5) flash attention
  fattn_kernel<<<dim3(15, 64), blk, 0, stream>>>(qkv, attn_o);
  // 6) out projection + residual(tgt)
  mgemm_kernel<false, false, true, false><<<dim3(2, MT), blk, 0, stream>>>(
      attn_o, sa_out_w, sa_out_b, tgt, sa_out, M, 256, 256);
  // 7) LN1 -> tgt1
  ln_kernel<<<M, blk, 0, stream>>>(sa_out, ln1_s, ln1_b, tgt1);
  // 8) q2 = tgt1 + query_pos
  add_kernel<<<(int)(E / 4 / 256), 256, 0, stream>>>((const float4*)tgt1, (const float4*)qpos,
                                                     (float4*)q2, (int)(E / 4));
  // 9) value projection -> bf16 (B*LV x 256)
  mgemm_kernel<false, false, false, true><<<dim3(2, (BDIM * LVTOT) / 128), blk, 0, stream>>>(
      memory, val_w, val_b, nullptr, valbf, BDIM * LVTOT, 256, 256);
  // 10) offsets projection
  mgemm_kernel<false, false, false, false><<<dim3(2, MT), blk, 0, stream>>>(
      q2, off_w, off_b, nullptr, offb, M, 256, 256);
  // 11) attention-weights projection
  mgemm_kernel<false, false, false, false><<<dim3(1, MT), blk, 0, stream>>>(
      q2, aw_w, aw_b, nullptr, awb, M, 128, 256);
  // 12) aw softmax (over 16 per head)
  awsm_kernel<<<M, 128, 0, stream>>>(awb);
  // 13) deformable sampling -> dfout
  deform_kernel<<<M, blk, 0, stream>>>((const __hip_bfloat16*)valbf, offb, awb, refp, dfout);
  // 14) co projection + residual(tgt1)
  mgemm_kernel<false, false, true, false><<<dim3(2, MT), blk, 0, stream>>>(
      dfout, co_w, co_b, tgt1, co_out, M, 256, 256);
  // 15) LN2 -> tgt2
  ln_kernel<<<M, blk, 0, stream>>>(co_out, ln2_s, ln2_b, tgt2);
  // 16) FFN1 + ReLU -> bf16 hidden
  mgemm_kernel<false, true, false, true><<<dim3(16, MT), blk, 0, stream>>>(
      tgt2, l1_w, l1_b, nullptr, hidden, M, 2048, 256);
  // 17) FFN2 + residual(tgt2), bf16 A
  mgemm_kernel<true, false, true, false><<<dim3(2, MT), blk, 0, stream>>>(
      hidden, l2_w, l2_b, tgt2, ffn_o, M, 256, 2048);
  // 18) LN3 -> out
  ln_kernel<<<M, blk, 0, stream>>>(ffn_o, ln3_s, ln3_b, (float*)d_out);
}

// Round 4
// 561.479 us; speedup vs baseline: 3.9991x; 1.3481x over previous
//
#include <hip/hip_runtime.h>
#include <hip/hip_bf16.h>

#define NQL 900
#define CDIM 256
#define BDIM 8
#define LVTOT 21760

typedef __bf16 bf16x8 __attribute__((ext_vector_type(8)));
typedef float f32x4 __attribute__((ext_vector_type(4)));
typedef uint u32x4 __attribute__((ext_vector_type(4)));
typedef uint u32x2 __attribute__((ext_vector_type(2)));

__device__ __forceinline__ ushort f2bf(float x) {
  uint u = __builtin_bit_cast(uint, x);
  u += 0x7fff + ((u >> 16) & 1);
  return (ushort)(u >> 16);
}

// ---------------- elementwise add (float4) ----------------
__global__ __launch_bounds__(256) void add_kernel(const float4* __restrict__ a,
                                                  const float4* __restrict__ b,
                                                  float4* __restrict__ o, int n4) {
  int i = blockIdx.x * 256 + threadIdx.x;
  if (i < n4) {
    float4 x = a[i], y = b[i];
    o[i] = make_float4(x.x + y.x, x.y + y.y, x.z + y.z, x.w + y.w);
  }
}

// ---------------- bf16 MFMA GEMM: C = A @ W^T + bias (+res)(+relu) ----------------
template <bool ABF16, bool RELU, bool HASRES, bool OUTBF16>
__global__ __launch_bounds__(256, 2) void mgemm_kernel(const void* __restrict__ Ap,
                                                       const float* __restrict__ W,
                                                       const float* __restrict__ bias,
                                                       const float* __restrict__ Rres,
                                                       void* __restrict__ Cout,
                                                       int M, int N, int K) {
  __shared__ ushort As[128 * 40];
  __shared__ ushort Bs[128 * 40];
  const int tid = threadIdx.x;
  const int m0 = blockIdx.y * 128, n0 = blockIdx.x * 128;
  const int wv = tid >> 6;
  const int wm = (wv >> 1) * 64, wn = (wv & 1) * 64;
  const int lane = tid & 63;
  const int lr = lane & 15, kq = lane >> 4;

  f32x4 acc[4][4] = {};

  for (int k0 = 0; k0 < K; k0 += 32) {
#pragma unroll
    for (int it = 0; it < 2; ++it) {
      int idx = it * 256 + tid;
      int r = idx >> 2, s = idx & 3;
      {
        int gm = min(m0 + r, M - 1);
        u32x4 u;
        if constexpr (ABF16) {
          u = *(const u32x4*)((const ushort*)Ap + (size_t)gm * K + k0 + s * 8);
        } else {
          const float* ap = (const float*)Ap + (size_t)gm * K + k0 + s * 8;
          float4 f0 = *(const float4*)ap;
          float4 f1 = *(const float4*)(ap + 4);
          u.x = f2bf(f0.x) | ((uint)f2bf(f0.y) << 16);
          u.y = f2bf(f0.z) | ((uint)f2bf(f0.w) << 16);
          u.z = f2bf(f1.x) | ((uint)f2bf(f1.y) << 16);
          u.w = f2bf(f1.z) | ((uint)f2bf(f1.w) << 16);
        }
        *(u32x4*)&As[r * 40 + s * 8] = u;
      }
      {
        int gn = min(n0 + r, N - 1);
        const float* wp = W + (size_t)gn * K + k0 + s * 8;
        float4 f0 = *(const float4*)wp;
        float4 f1 = *(const float4*)(wp + 4);
        u32x4 u;
        u.x = f2bf(f0.x) | ((uint)f2bf(f0.y) << 16);
        u.y = f2bf(f0.z) | ((uint)f2bf(f0.w) << 16);
        u.z = f2bf(f1.x) | ((uint)f2bf(f1.y) << 16);
        u.w = f2bf(f1.z) | ((uint)f2bf(f1.w) << 16);
        *(u32x4*)&Bs[r * 40 + s * 8] = u;
      }
    }
    __syncthreads();
    bf16x8 af[4], bq[4];
#pragma unroll
    for (int m = 0; m < 4; ++m)
      af[m] = __builtin_bit_cast(bf16x8, *(const u32x4*)&As[(wm + m * 16 + lr) * 40 + kq * 8]);
#pragma unroll
    for (int n = 0; n < 4; ++n)
      bq[n] = __builtin_bit_cast(bf16x8, *(const u32x4*)&Bs[(wn + n * 16 + lr) * 40 + kq * 8]);
#pragma unroll
    for (int m = 0; m < 4; ++m)
#pragma unroll
      for (int n = 0; n < 4; ++n)
        acc[m][n] = __builtin_amdgcn_mfma_f32_16x16x32_bf16(af[m], bq[n], acc[m][n], 0, 0, 0);
    __syncthreads();
  }

#pragma unroll
  for (int n = 0; n < 4; ++n) {
    int gcol = n0 + wn + n * 16 + lr;
    float bv = bias[gcol];
#pragma unroll
    for (int m = 0; m < 4; ++m) {
      int rbase = m0 + wm + m * 16 + kq * 4;
#pragma unroll
      for (int j = 0; j < 4; ++j) {
        int grow = rbase + j;
        if (grow >= M) continue;
        float v = acc[m][n][j] + bv;
        if (HASRES) v += Rres[(size_t)grow * N + gcol];
        if (RELU) v = fmaxf(v, 0.f);
        if (OUTBF16)
          ((ushort*)Cout)[(size_t)grow * N + gcol] = f2bf(v);
        else
          ((float*)Cout)[(size_t)grow * N + gcol] = v;
      }
    }
  }
}

// ---------------- V transpose: tmp_v bf16 [b*900+q][256] -> vt bf16 [(bh*32+d)][960] ----------------
__global__ __launch_bounds__(256) void vt_kernel(const ushort* __restrict__ tmp_v,
                                                 ushort* __restrict__ vt) {
  __shared__ ushort Ls[64 * 40];
  const int qt = blockIdx.x;   // 0..14
  const int bh = blockIdx.y;   // 0..63
  const int b = bh >> 3, h = bh & 7;
  const int tid = threadIdx.x;
  const int q0 = qt * 64;
  {
    int r = tid >> 2, c = (tid & 3) * 8;
    int gq = min(q0 + r, NQL - 1);
    u32x4 u = *(const u32x4*)(tmp_v + ((size_t)(b * NQL + gq) * 256) + h * 32 + c);
    *(u32x4*)&Ls[r * 40 + c] = u;
  }
  __syncthreads();
  {
    int d = tid >> 3, qw = (tid & 7) * 8;
    u32x4 u;
    uint w[8];
#pragma unroll
    for (int j = 0; j < 8; ++j) w[j] = Ls[(qw + j) * 40 + d];
    u.x = w[0] | (w[1] << 16);
    u.y = w[2] | (w[3] << 16);
    u.z = w[4] | (w[5] << 16);
    u.w = w[6] | (w[7] << 16);
    *(u32x4*)(vt + ((size_t)(bh * 32 + d) * 960) + q0 + qw) = u;
  }
}

// ---------------- MFMA flash self-attention ----------------
// grid (15 qtiles, 64 bh), 4 waves; wave handles 16 queries.
// qk: bf16 [b*900+q][512] (cols 0..255 = Q unscaled, 256..511 = K), vt: bf16 [(bh*32+d)][960]
__global__ __launch_bounds__(256, 2) void fattn_kernel(const ushort* __restrict__ qk,
                                                       const ushort* __restrict__ vt,
                                                       float* __restrict__ out) {
  __shared__ ushort Ks[64 * 40];
  __shared__ ushort Vs[32 * 72];
  __shared__ ushort Ps[4][16 * 72];
  const int qt = blockIdx.x, bh = blockIdx.y;
  const int b = bh >> 3, h = bh & 7;
  const int tid = threadIdx.x;
  const int wv = tid >> 6, lane = tid & 63;
  const int lq = lane & 15, hi = lane >> 4;
  const int q0 = qt * 64 + wv * 16;
  const float SC = 0.17677669529663689f;

  // Q B-frag: col q = q0+lq, k(d) = hi*8..+7
  bf16x8 qfrag;
  {
    int qrow = min(q0 + lq, NQL - 1);
    qfrag = __builtin_bit_cast(bf16x8,
        *(const u32x4*)(qk + (size_t)(b * NQL + qrow) * 512 + h * 32 + hi * 8));
  }

  f32x4 o0 = {}, o1 = {};
  float mrow = -1e30f, lrow = 0.f;

  for (int kt = 0; kt < 15; ++kt) {
    const int k0 = kt * 64;
    __syncthreads();
    {  // stage K tile [64 keys][32 d]
      int r = tid >> 2, c = (tid & 3) * 8;
      int gk = min(k0 + r, NQL - 1);
      u32x4 u = *(const u32x4*)(qk + (size_t)(b * NQL + gk) * 512 + 256 + h * 32 + c);
      *(u32x4*)&Ks[r * 40 + c] = u;
    }
    {  // stage V^T tile [32 d][64 keys]
      int r = tid >> 3, c = (tid & 7) * 8;
      u32x4 u = *(const u32x4*)(vt + (size_t)(bh * 32 + r) * 960 + k0 + c);
      *(u32x4*)&Vs[r * 72 + c] = u;
    }
    __syncthreads();

    // S^T[key][q] via 4 MFMAs: A = K rows, B = Q
    f32x4 st[4];
#pragma unroll
    for (int mt = 0; mt < 4; ++mt) {
      bf16x8 kf = __builtin_bit_cast(bf16x8, *(const u32x4*)&Ks[(mt * 16 + lq) * 40 + hi * 8]);
      f32x4 z = {};
      st[mt] = __builtin_amdgcn_mfma_f32_16x16x32_bf16(kf, qfrag, z, 0, 0, 0);
    }
    // softmax over keys for q = q0+lq (this lane's 16 values + xor16/32 partners)
    float sv[4][4];
    float lmax = -1e30f;
#pragma unroll
    for (int mt = 0; mt < 4; ++mt)
#pragma unroll
      for (int j = 0; j < 4; ++j) {
        int key = k0 + mt * 16 + hi * 4 + j;
        float v = st[mt][j] * SC;
        v = (key < NQL) ? v : -1e30f;
        sv[mt][j] = v;
        lmax = fmaxf(lmax, v);
      }
    lmax = fmaxf(lmax, __shfl_xor(lmax, 16));
    lmax = fmaxf(lmax, __shfl_xor(lmax, 32));
    float mnew = fmaxf(mrow, lmax);
    float rs = __expf(mrow - mnew);
    float lsum = 0.f;
    uint pw[4][2];
#pragma unroll
    for (int mt = 0; mt < 4; ++mt) {
      float p0 = __expf(sv[mt][0] - mnew);
      float p1 = __expf(sv[mt][1] - mnew);
      float p2 = __expf(sv[mt][2] - mnew);
      float p3 = __expf(sv[mt][3] - mnew);
      lsum += (p0 + p1) + (p2 + p3);
      pw[mt][0] = f2bf(p0) | ((uint)f2bf(p1) << 16);
      pw[mt][1] = f2bf(p2) | ((uint)f2bf(p3) << 16);
    }
    lsum += __shfl_xor(lsum, 16);
    lsum += __shfl_xor(lsum, 32);
    lrow = lrow * rs + lsum;
    mrow = mnew;
    // broadcast rescale to O row layout (row q = hi*4+j)
#pragma unroll
    for (int j = 0; j < 4; ++j) {
      float rsj = __shfl(rs, hi * 4 + j);
      o0[j] *= rsj;
      o1[j] *= rsj;
    }
    // write P (bf16) to per-wave LDS: P[q=lq][key_local]
#pragma unroll
    for (int mt = 0; mt < 4; ++mt) {
      u32x2 u;
      u.x = pw[mt][0];
      u.y = pw[mt][1];
      *(u32x2*)&Ps[wv][lq * 72 + mt * 16 + hi * 4] = u;
    }
    // PV: O[q][d] += P[q][key] @ V^T, 4 MFMAs
#pragma unroll
    for (int k2 = 0; k2 < 2; ++k2) {
      bf16x8 pa = __builtin_bit_cast(bf16x8, *(const u32x4*)&Ps[wv][lq * 72 + k2 * 32 + hi * 8]);
      bf16x8 vb0 = __builtin_bit_cast(bf16x8, *(const u32x4*)&Vs[(0 * 16 + lq) * 72 + k2 * 32 + hi * 8]);
      bf16x8 vb1 = __builtin_bit_cast(bf16x8, *(const u32x4*)&Vs[(1 * 16 + lq) * 72 + k2 * 32 + hi * 8]);
      o0 = __builtin_amdgcn_mfma_f32_16x16x32_bf16(pa, vb0, o0, 0, 0, 0);
      o1 = __builtin_amdgcn_mfma_f32_16x16x32_bf16(pa, vb1, o1, 0, 0, 0);
    }
  }

  // epilogue: divide by l (broadcast per row), store
#pragma unroll
  for (int j = 0; j < 4; ++j) {
    float lj = __shfl(lrow, hi * 4 + j);
    float inv = 1.f / lj;
    int gq = q0 + hi * 4 + j;
    if (gq < NQL) {
      float* op = out + (size_t)(b * NQL + gq) * 256 + h * 32;
      op[lq] = o0[j] * inv;
      op[16 + lq] = o1[j] * inv;
    }
  }
}

// ---------------- LayerNorm over 256 ----------------
__global__ __launch_bounds__(256) void ln_kernel(const float* __restrict__ x,
                                                 const float* __restrict__ s,
                                                 const float* __restrict__ bb,
                                                 float* __restrict__ out) {
  int row = blockIdx.x, tid = threadIdx.x;
  float v = x[(size_t)row * 256 + tid];
  __shared__ float r1[256], r2[256];
  r1[tid] = v;
  r2[tid] = v * v;
  __syncthreads();
  for (int st = 128; st > 0; st >>= 1) {
    if (tid < st) { r1[tid] += r1[tid + st]; r2[tid] += r2[tid + st]; }
    __syncthreads();
  }
  float m = r1[0] * (1.f / 256);
  float var = r2[0] * (1.f / 256) - m * m;
  out[(size_t)row * 256 + tid] = (v - m) * rsqrtf(var + 1e-5f) * s[tid] + bb[tid];
}

// ---------------- aw softmax over groups of 16 ----------------
__global__ __launch_bounds__(128) void awsm_kernel(float* __restrict__ aw) {
  int row = blockIdx.x, tid = threadIdx.x;
  float v = aw[(size_t)row * 128 + tid];
  float m = v;
  for (int d = 1; d < 16; d <<= 1) m = fmaxf(m, __shfl_xor(m, d));
  float e = expf(v - m);
  float ssum = e;
  for (int d = 1; d < 16; d <<= 1) ssum += __shfl_xor(ssum, d);
  aw[(size_t)row * 128 + tid] = e / ssum;
}

// ---------------- deformable sampling: block per (b,q), thread = (h,d) ----------------
__global__ __launch_bounds__(256) void deform_kernel(const __hip_bfloat16* __restrict__ value,
                                                     const float* __restrict__ offb,
                                                     const float* __restrict__ awb,
                                                     const float* __restrict__ refp,
                                                     float* __restrict__ dfout) {
  const int Hs[4] = {128, 64, 32, 16};
  const int Stl[4] = {0, 16384, 20480, 21504};
  int row = blockIdx.x;
  int b = row / NQL;
  int tid = threadIdx.x;
  int h = tid >> 5, d = tid & 31;
  const float* off = offb + (size_t)row * 256;
  const float* aw = awb + (size_t)row * 128;
  const float* ref = refp + (size_t)row * 8;
  const __hip_bfloat16* vb = value + (size_t)b * LVTOT * 256 + h * 32 + d;
  float acc = 0.f;
#pragma unroll
  for (int l = 0; l < 4; ++l) {
    int Wi = Hs[l], Hi = Hs[l];
    float Wl = (float)Wi, Hl = (float)Hi;
    int st = Stl[l];
    float rx = ref[l * 2 + 0], ry = ref[l * 2 + 1];
#pragma unroll
    for (int p = 0; p < 4; ++p) {
      int oi = ((h * 4 + l) * 4 + p) * 2;
      float x = (rx + off[oi] / Wl) * Wl - 0.5f;
      float y = (ry + off[oi + 1] / Hl) * Hl - 0.5f;
      float w = aw[h * 16 + l * 4 + p];
      float x0f = floorf(x), y0f = floorf(y);
      float wx = x - x0f, wy = y - y0f;
      int xi0 = (int)x0f, yi0 = (int)y0f;
      float samp = 0.f;
#pragma unroll
      for (int dy = 0; dy < 2; ++dy) {
#pragma unroll
        for (int dx = 0; dx < 2; ++dx) {
          int xi = xi0 + dx, yi = yi0 + dy;
          float tw = (dx ? wx : 1.f - wx) * (dy ? wy : 1.f - wy);
          bool valid = (xi >= 0) && (xi < Wi) && (yi >= 0) && (yi < Hi);
          int xc = min(max(xi, 0), Wi - 1);
          int yc = min(max(yi, 0), Hi - 1);
          float vv = __bfloat162float(vb[(size_t)(st + yc * Wi + xc) * 256]);
          samp += valid ? tw * vv : 0.f;
        }
      }
      acc = fmaf(w, samp, acc);
    }
  }
  dfout[(size_t)row * 256 + tid] = acc;
}

extern "C" void kernel_launch(void* const* d_in, const int* in_sizes, int n_in,
                              void* d_out, int out_size, void* d_ws, size_t ws_size,
                              hipStream_t stream) {
  const float* tgt = (const float*)d_in[0];
  const float* memory = (const float*)d_in[1];
  const float* qpos = (const float*)d_in[2];
  const float* refp = (const float*)d_in[3];
  const float* sa_in_w = (const float*)d_in[4];
  const float* sa_in_b = (const float*)d_in[5];
  const float* sa_out_w = (const float*)d_in[6];
  const float* sa_out_b = (const float*)d_in[7];
  const float* off_w = (const float*)d_in[8];
  const float* off_b = (const float*)d_in[9];
  const float* aw_w = (const float*)d_in[10];
  const float* aw_b = (const float*)d_in[11];
  const float* val_w = (const float*)d_in[12];
  const float* val_b = (const float*)d_in[13];
  const float* co_w = (const float*)d_in[14];
  const float* co_b = (const float*)d_in[15];
  const float* l1_w = (const float*)d_in[16];
  const float* l1_b = (const float*)d_in[17];
  const float* l2_w = (const float*)d_in[18];
  const float* l2_b = (const float*)d_in[19];
  const float* ln1_s = (const float*)d_in[20];
  const float* ln1_b = (const float*)d_in[21];
  const float* ln2_s = (const float*)d_in[22];
  const float* ln2_b = (const float*)d_in[23];
  const float* ln3_s = (const float*)d_in[24];
  const float* ln3_b = (const float*)d_in[25];

  float* ws = (float*)d_ws;
  const size_t E = (size_t)BDIM * NQL * CDIM;  // 1,843,200
  // phase SA
  float* q_add = ws;                         // [0,E)
  ushort* vt = (ushort*)(ws + E);            // bf16 [64*32][960] = 3.93MB in [E,2E)
  float* attn_o = ws + 4 * E;                // [4E,5E)
  ushort* tmp_qk = (ushort*)(ws + 5 * E);    // bf16 [7200][512] in [5E,7E)
  ushort* tmp_v = (ushort*)(ws + 7 * E);     // bf16 [7200][256] in [7E,8E)
  float* sa_out = ws + 5 * E;                // reuse after fattn
  // phase deform
  float* q2 = ws;                            // [0,E)
  float* offb = ws + E;                      // [E,2E)
  float* awb = ws + 2 * E;                   // [2E,2.5E)
  float* dfout = ws + 3 * E;                 // [3E,4E)
  float* co_out = ws + 4 * E;                // [4E,5E)
  // phase FFN
  ushort* hidden = (ushort*)ws;              // bf16 [7200][2048] = [0,4E)
  // persistent
  float* tgt1 = ws + 8 * E;
  float* tgt2 = ws + 9 * E;
  float* ffn_o = ws + 10 * E;
  ushort* valbf = (ushort*)(ws + 11 * E);

  const int M = BDIM * NQL;  // 7200
  const int MT = (M + 127) / 128;  // 57
  dim3 blk(256);

  // 1) q = tgt + query_pos
  add_kernel<<<(int)(E / 4 / 256), 256, 0, stream>>>((const float4*)tgt, (const float4*)qpos,
                                                     (float4*)q_add, (int)(E / 4));
  // 2) q,k projections -> bf16 [M][512]
  mgemm_kernel<false, false, false, true><<<dim3(4, MT), blk, 0, stream>>>(
      q_add, sa_in_w, sa_in_b, nullptr, tmp_qk, M, 512, 256);
  // 3) v projection -> bf16 [M][256]
  mgemm_kernel<false, false, false, true><<<dim3(2, MT), blk, 0, stream>>>(
      tgt, sa_in_w + 512 * 256, sa_in_b + 512, nullptr, tmp_v, M, 256, 256);
  // 4) V transpose -> vt
  vt_kernel<<<dim3(15, 64), blk, 0, stream>>>(tmp_v, vt);
  // 5) MFMA flash attention
  fattn_kernel<<<dim3(15, 64), blk, 0, stream>>>(tmp_qk, vt, attn_o);
  // 6) out projection + residual(tgt)
  mgemm_kernel<false, false, true, false><<<dim3(2, MT), blk, 0, stream>>>(
      attn_o, sa_out_w, sa_out_b, tgt, sa_out, M, 256, 256);
  // 7) LN1 -> tgt1
  ln_kernel<<<M, blk, 0, stream>>>(sa_out, ln1_s, ln1_b, tgt1);
  // 8) q2 = tgt1 + query_pos
  add_kernel<<<(int)(E / 4 / 256), 256, 0, stream>>>((const float4*)tgt1, (const float4*)qpos,
                                                     (float4*)q2, (int)(E / 4));
  // 9) value projection -> bf16
  mgemm_kernel<false, false, false, true><<<dim3(2, (BDIM * LVTOT) / 128), blk, 0, stream>>>(
      memory, val_w, val_b, nullptr, valbf, BDIM * LVTOT, 256, 256);
  // 10) offsets projection
  mgemm_kernel<false, false, false, false><<<dim3(2, MT), blk, 0, stream>>>(
      q2, off_w, off_b, nullptr, offb, M, 256, 256);
  // 11) attention-weights projection
  mgemm_kernel<false, false, false, false><<<dim3(1, MT), blk, 0, stream>>>(
      q2, aw_w, aw_b, nullptr, awb, M, 128, 256);
  // 12) aw softmax
  awsm_kernel<<<M, 128, 0, stream>>>(awb);
  // 13) deformable sampling
  deform_kernel<<<M, blk, 0, stream>>>((const __hip_bfloat16*)valbf, offb, awb, refp, dfout);
  // 14) co projection + residual(tgt1)
  mgemm_kernel<false, false, true, false><<<dim3(2, MT), blk, 0, stream>>>(
      dfout, co_w, co_b, tgt1, co_out, M, 256, 256);
  // 15) LN2 -> tgt2
  ln_kernel<<<M, blk, 0, stream>>>(co_out, ln2_s, ln2_b, tgt2);
  // 16) FFN1 + ReLU -> bf16 hidden
  mgemm_kernel<false, true, false, true><<<dim3(16, MT), blk, 0, stream>>>(
      tgt2, l1_w, l1_b, nullptr, hidden, M, 2048, 256);
  // 17) FFN2 + residual(tgt2), bf16 A
  mgemm_kernel<true, false, true, false><<<dim3(2, MT), blk, 0, stream>>>(
      hidden, l2_w, l2_b, tgt2, ffn_o, M, 256, 2048);
  // 18) LN3 -> out
  ln_kernel<<<M, blk, 0, stream>>>(ffn_o, ln3_s, ln3_b, (float*)d_out);
}

// Round 5
// 409.658 us; speedup vs baseline: 5.4812x; 1.3706x over previous
//
#include <hip/hip_runtime.h>
#include <hip/hip_bf16.h>

#define NQL 900
#define CDIM 256
#define BDIM 8
#define LVTOT 21760

typedef __bf16 bf16x8 __attribute__((ext_vector_type(8)));
typedef float f32x4 __attribute__((ext_vector_type(4)));
typedef uint u32x4 __attribute__((ext_vector_type(4)));
typedef uint u32x2 __attribute__((ext_vector_type(2)));

__device__ __forceinline__ ushort f2bf(float x) {
  uint u = __builtin_bit_cast(uint, x);
  u += 0x7fff + ((u >> 16) & 1);
  return (ushort)(u >> 16);
}

// ---------------- bf16 MFMA GEMM: C = (A [+A2]) @ W^T + bias (+res)(+relu) ----------------
// A: M x K (fp32 or bf16 per ABF16), optional A2 fp32 added to A, W: N x K fp32.
// BM=BN=128, BK=32, 4 waves of 64x64. N % 128 == 0, K % 32 == 0.
// OUTBF16 epilogue stages C in LDS -> 16B/lane coalesced stores (full-line HBM writes).
template <bool ABF16, bool AADD, bool RELU, bool HASRES, bool OUTBF16>
__global__ __launch_bounds__(256, 2) void mgemm_kernel(const void* __restrict__ Ap,
                                                       const float* __restrict__ A2p,
                                                       const float* __restrict__ W,
                                                       const float* __restrict__ bias,
                                                       const float* __restrict__ Rres,
                                                       void* __restrict__ Cout,
                                                       int M, int N, int K) {
  __shared__ ushort smem[17408];  // As[0,5120) Bs[5120,10240); epilogue Cs uses [0,17408)
  ushort* As = smem;
  ushort* Bs = smem + 5120;
  const int tid = threadIdx.x;
  const int m0 = blockIdx.y * 128, n0 = blockIdx.x * 128;
  const int wv = tid >> 6;
  const int wm = (wv >> 1) * 64, wn = (wv & 1) * 64;
  const int lane = tid & 63;
  const int lr = lane & 15, kq = lane >> 4;

  f32x4 acc[4][4] = {};

  float4 pa[2][2], pb[2][2];
  u32x4 pa16[2];

  auto load_tiles = [&](int k0) {
#pragma unroll
    for (int it = 0; it < 2; ++it) {
      int idx = it * 256 + tid;
      int r = idx >> 2, s = (idx & 3) << 3;
      int gm = min(m0 + r, M - 1);
      if constexpr (ABF16) {
        pa16[it] = *(const u32x4*)((const ushort*)Ap + (size_t)gm * K + k0 + s);
      } else {
        const float* ap = (const float*)Ap + (size_t)gm * K + k0 + s;
        pa[it][0] = *(const float4*)ap;
        pa[it][1] = *(const float4*)(ap + 4);
        if constexpr (AADD) {
          const float* ap2 = A2p + (size_t)gm * K + k0 + s;
          float4 q0 = *(const float4*)ap2;
          float4 q1 = *(const float4*)(ap2 + 4);
          pa[it][0].x += q0.x; pa[it][0].y += q0.y; pa[it][0].z += q0.z; pa[it][0].w += q0.w;
          pa[it][1].x += q1.x; pa[it][1].y += q1.y; pa[it][1].z += q1.z; pa[it][1].w += q1.w;
        }
      }
      int gn = min(n0 + r, N - 1);
      const float* wp = W + (size_t)gn * K + k0 + s;
      pb[it][0] = *(const float4*)wp;
      pb[it][1] = *(const float4*)(wp + 4);
    }
  };

  auto store_tiles = [&]() {
#pragma unroll
    for (int it = 0; it < 2; ++it) {
      int idx = it * 256 + tid;
      int r = idx >> 2, s = (idx & 3) << 3;
      u32x4 u;
      if constexpr (ABF16) {
        u = pa16[it];
      } else {
        u.x = f2bf(pa[it][0].x) | ((uint)f2bf(pa[it][0].y) << 16);
        u.y = f2bf(pa[it][0].z) | ((uint)f2bf(pa[it][0].w) << 16);
        u.z = f2bf(pa[it][1].x) | ((uint)f2bf(pa[it][1].y) << 16);
        u.w = f2bf(pa[it][1].z) | ((uint)f2bf(pa[it][1].w) << 16);
      }
      *(u32x4*)&As[r * 40 + s] = u;
      u32x4 w;
      w.x = f2bf(pb[it][0].x) | ((uint)f2bf(pb[it][0].y) << 16);
      w.y = f2bf(pb[it][0].z) | ((uint)f2bf(pb[it][0].w) << 16);
      w.z = f2bf(pb[it][1].x) | ((uint)f2bf(pb[it][1].y) << 16);
      w.w = f2bf(pb[it][1].z) | ((uint)f2bf(pb[it][1].w) << 16);
      *(u32x4*)&Bs[r * 40 + s] = w;
    }
  };

  load_tiles(0);
  for (int k0 = 0; k0 < K; k0 += 32) {
    store_tiles();
    __syncthreads();
    if (k0 + 32 < K) load_tiles(k0 + 32);  // in flight under MFMA
    bf16x8 af[4], bq[4];
#pragma unroll
    for (int m = 0; m < 4; ++m)
      af[m] = __builtin_bit_cast(bf16x8, *(const u32x4*)&As[(wm + m * 16 + lr) * 40 + kq * 8]);
#pragma unroll
    for (int n = 0; n < 4; ++n)
      bq[n] = __builtin_bit_cast(bf16x8, *(const u32x4*)&Bs[(wn + n * 16 + lr) * 40 + kq * 8]);
#pragma unroll
    for (int m = 0; m < 4; ++m)
#pragma unroll
      for (int n = 0; n < 4; ++n)
        acc[m][n] = __builtin_amdgcn_mfma_f32_16x16x32_bf16(af[m], bq[n], acc[m][n], 0, 0, 0);
    __syncthreads();
  }

  if constexpr (OUTBF16) {
    // stage bf16 C tile in LDS (stride 136), then coalesced 16B/lane stores
    ushort* Cs = smem;
#pragma unroll
    for (int n = 0; n < 4; ++n) {
      int col = wn + n * 16 + lr;
      float bv = bias[n0 + col];
#pragma unroll
      for (int m = 0; m < 4; ++m) {
#pragma unroll
        for (int j = 0; j < 4; ++j) {
          int row = wm + m * 16 + kq * 4 + j;
          float v = acc[m][n][j] + bv;
          if (RELU) v = fmaxf(v, 0.f);
          Cs[row * 136 + col] = f2bf(v);
        }
      }
    }
    __syncthreads();
#pragma unroll
    for (int p = 0; p < 8; ++p) {
      int row = p * 16 + (tid >> 4);
      int grow = m0 + row;
      if (grow < M) {
        u32x4 u = *(const u32x4*)&Cs[row * 136 + (tid & 15) * 8];
        *(u32x4*)((ushort*)Cout + (size_t)grow * N + n0 + (tid & 15) * 8) = u;
      }
    }
  } else {
#pragma unroll
    for (int n = 0; n < 4; ++n) {
      int gcol = n0 + wn + n * 16 + lr;
      float bv = bias[gcol];
#pragma unroll
      for (int m = 0; m < 4; ++m) {
        int rbase = m0 + wm + m * 16 + kq * 4;
#pragma unroll
        for (int j = 0; j < 4; ++j) {
          int grow = rbase + j;
          if (grow >= M) continue;
          float v = acc[m][n][j] + bv;
          if (HASRES) v += Rres[(size_t)grow * N + gcol];
          if (RELU) v = fmaxf(v, 0.f);
          ((float*)Cout)[(size_t)grow * N + gcol] = v;
        }
      }
    }
  }
}

// ---------------- V transpose: tmp_v bf16 [b*900+q][256] -> vt bf16 [(bh*32+d)][960] ----------------
__global__ __launch_bounds__(256) void vt_kernel(const ushort* __restrict__ tmp_v,
                                                 ushort* __restrict__ vt) {
  __shared__ ushort Ls[64 * 40];
  const int qt = blockIdx.x;
  const int bh = blockIdx.y;
  const int b = bh >> 3, h = bh & 7;
  const int tid = threadIdx.x;
  const int q0 = qt * 64;
  {
    int r = tid >> 2, c = (tid & 3) * 8;
    int gq = min(q0 + r, NQL - 1);
    u32x4 u = *(const u32x4*)(tmp_v + ((size_t)(b * NQL + gq) * 256) + h * 32 + c);
    *(u32x4*)&Ls[r * 40 + c] = u;
  }
  __syncthreads();
  {
    int d = tid >> 3, qw = (tid & 7) * 8;
    u32x4 u;
    uint w[8];
#pragma unroll
    for (int j = 0; j < 8; ++j) w[j] = Ls[(qw + j) * 40 + d];
    u.x = w[0] | (w[1] << 16);
    u.y = w[2] | (w[3] << 16);
    u.z = w[4] | (w[5] << 16);
    u.w = w[6] | (w[7] << 16);
    *(u32x4*)(vt + ((size_t)(bh * 32 + d) * 960) + q0 + qw) = u;
  }
}

// ---------------- MFMA flash self-attention ----------------
__global__ __launch_bounds__(256, 2) void fattn_kernel(const ushort* __restrict__ qk,
                                                       const ushort* __restrict__ vt,
                                                       float* __restrict__ out) {
  __shared__ ushort Ks[64 * 40];
  __shared__ ushort Vs[32 * 72];
  __shared__ ushort Ps[4][16 * 72];
  const int qt = blockIdx.x, bh = blockIdx.y;
  const int b = bh >> 3, h = bh & 7;
  const int tid = threadIdx.x;
  const int wv = tid >> 6, lane = tid & 63;
  const int lq = lane & 15, hi = lane >> 4;
  const int q0 = qt * 64 + wv * 16;
  const float SC = 0.17677669529663689f;

  bf16x8 qfrag;
  {
    int qrow = min(q0 + lq, NQL - 1);
    qfrag = __builtin_bit_cast(bf16x8,
        *(const u32x4*)(qk + (size_t)(b * NQL + qrow) * 512 + h * 32 + hi * 8));
  }

  f32x4 o0 = {}, o1 = {};
  float mrow = -1e30f, lrow = 0.f;

  for (int kt = 0; kt < 15; ++kt) {
    const int k0 = kt * 64;
    __syncthreads();
    {
      int r = tid >> 2, c = (tid & 3) * 8;
      int gk = min(k0 + r, NQL - 1);
      u32x4 u = *(const u32x4*)(qk + (size_t)(b * NQL + gk) * 512 + 256 + h * 32 + c);
      *(u32x4*)&Ks[r * 40 + c] = u;
    }
    {
      int r = tid >> 3, c = (tid & 7) * 8;
      u32x4 u = *(const u32x4*)(vt + (size_t)(bh * 32 + r) * 960 + k0 + c);
      *(u32x4*)&Vs[r * 72 + c] = u;
    }
    __syncthreads();

    f32x4 st[4];
#pragma unroll
    for (int mt = 0; mt < 4; ++mt) {
      bf16x8 kf = __builtin_bit_cast(bf16x8, *(const u32x4*)&Ks[(mt * 16 + lq) * 40 + hi * 8]);
      f32x4 z = {};
      st[mt] = __builtin_amdgcn_mfma_f32_16x16x32_bf16(kf, qfrag, z, 0, 0, 0);
    }
    float sv[4][4];
    float lmax = -1e30f;
#pragma unroll
    for (int mt = 0; mt < 4; ++mt)
#pragma unroll
      for (int j = 0; j < 4; ++j) {
        int key = k0 + mt * 16 + hi * 4 + j;
        float v = st[mt][j] * SC;
        v = (key < NQL) ? v : -1e30f;
        sv[mt][j] = v;
        lmax = fmaxf(lmax, v);
      }
    lmax = fmaxf(lmax, __shfl_xor(lmax, 16));
    lmax = fmaxf(lmax, __shfl_xor(lmax, 32));
    float mnew = fmaxf(mrow, lmax);
    float rs = __expf(mrow - mnew);
    float lsum = 0.f;
    uint pw[4][2];
#pragma unroll
    for (int mt = 0; mt < 4; ++mt) {
      float p0 = __expf(sv[mt][0] - mnew);
      float p1 = __expf(sv[mt][1] - mnew);
      float p2 = __expf(sv[mt][2] - mnew);
      float p3 = __expf(sv[mt][3] - mnew);
      lsum += (p0 + p1) + (p2 + p3);
      pw[mt][0] = f2bf(p0) | ((uint)f2bf(p1) << 16);
      pw[mt][1] = f2bf(p2) | ((uint)f2bf(p3) << 16);
    }
    lsum += __shfl_xor(lsum, 16);
    lsum += __shfl_xor(lsum, 32);
    lrow = lrow * rs + lsum;
    mrow = mnew;
#pragma unroll
    for (int j = 0; j < 4; ++j) {
      float rsj = __shfl(rs, hi * 4 + j);
      o0[j] *= rsj;
      o1[j] *= rsj;
    }
#pragma unroll
    for (int mt = 0; mt < 4; ++mt) {
      u32x2 u;
      u.x = pw[mt][0];
      u.y = pw[mt][1];
      *(u32x2*)&Ps[wv][lq * 72 + mt * 16 + hi * 4] = u;
    }
#pragma unroll
    for (int k2 = 0; k2 < 2; ++k2) {
      bf16x8 pa = __builtin_bit_cast(bf16x8, *(const u32x4*)&Ps[wv][lq * 72 + k2 * 32 + hi * 8]);
      bf16x8 vb0 = __builtin_bit_cast(bf16x8, *(const u32x4*)&Vs[(0 * 16 + lq) * 72 + k2 * 32 + hi * 8]);
      bf16x8 vb1 = __builtin_bit_cast(bf16x8, *(const u32x4*)&Vs[(1 * 16 + lq) * 72 + k2 * 32 + hi * 8]);
      o0 = __builtin_amdgcn_mfma_f32_16x16x32_bf16(pa, vb0, o0, 0, 0, 0);
      o1 = __builtin_amdgcn_mfma_f32_16x16x32_bf16(pa, vb1, o1, 0, 0, 0);
    }
  }

#pragma unroll
  for (int j = 0; j < 4; ++j) {
    float lj = __shfl(lrow, hi * 4 + j);
    float inv = 1.f / lj;
    int gq = q0 + hi * 4 + j;
    if (gq < NQL) {
      float* op = out + (size_t)(b * NQL + gq) * 256 + h * 32;
      op[lq] = o0[j] * inv;
      op[16 + lq] = o1[j] * inv;
    }
  }
}

// ---------------- LayerNorm over 256 ----------------
__global__ __launch_bounds__(256) void ln_kernel(const float* __restrict__ x,
                                                 const float* __restrict__ s,
                                                 const float* __restrict__ bb,
                                                 float* __restrict__ out) {
  int row = blockIdx.x, tid = threadIdx.x;
  float v = x[(size_t)row * 256 + tid];
  __shared__ float r1[256], r2[256];
  r1[tid] = v;
  r2[tid] = v * v;
  __syncthreads();
  for (int st = 128; st > 0; st >>= 1) {
    if (tid < st) { r1[tid] += r1[tid + st]; r2[tid] += r2[tid + st]; }
    __syncthreads();
  }
  float m = r1[0] * (1.f / 256);
  float var = r2[0] * (1.f / 256) - m * m;
  out[(size_t)row * 256 + tid] = (v - m) * rsqrtf(var + 1e-5f) * s[tid] + bb[tid];
}

// ---------------- aw softmax over groups of 16 ----------------
__global__ __launch_bounds__(128) void awsm_kernel(float* __restrict__ aw) {
  int row = blockIdx.x, tid = threadIdx.x;
  float v = aw[(size_t)row * 128 + tid];
  float m = v;
  for (int d = 1; d < 16; d <<= 1) m = fmaxf(m, __shfl_xor(m, d));
  float e = expf(v - m);
  float ssum = e;
  for (int d = 1; d < 16; d <<= 1) ssum += __shfl_xor(ssum, d);
  aw[(size_t)row * 128 + tid] = e / ssum;
}

// ---------------- deformable sampling: block per (b,q), thread = (h,d) ----------------
__global__ __launch_bounds__(256) void deform_kernel(const __hip_bfloat16* __restrict__ value,
                                                     const float* __restrict__ offb,
                                                     const float* __restrict__ awb,
                                                     const float* __restrict__ refp,
                                                     float* __restrict__ dfout) {
  const int Hs[4] = {128, 64, 32, 16};
  const int Stl[4] = {0, 16384, 20480, 21504};
  int row = blockIdx.x;
  int b = row / NQL;
  int tid = threadIdx.x;
  int h = tid >> 5, d = tid & 31;
  const float* off = offb + (size_t)row * 256;
  const float* aw = awb + (size_t)row * 128;
  const float* ref = refp + (size_t)row * 8;
  const __hip_bfloat16* vb = value + (size_t)b * LVTOT * 256 + h * 32 + d;
  float acc = 0.f;
#pragma unroll
  for (int l = 0; l < 4; ++l) {
    int Wi = Hs[l], Hi = Hs[l];
    float Wl = (float)Wi, Hl = (float)Hi;
    int st = Stl[l];
    float rx = ref[l * 2 + 0], ry = ref[l * 2 + 1];
#pragma unroll
    for (int p = 0; p < 4; ++p) {
      int oi = ((h * 4 + l) * 4 + p) * 2;
      float x = (rx + off[oi] / Wl) * Wl - 0.5f;
      float y = (ry + off[oi + 1] / Hl) * Hl - 0.5f;
      float w = aw[h * 16 + l * 4 + p];
      float x0f = floorf(x), y0f = floorf(y);
      float wx = x - x0f, wy = y - y0f;
      int xi0 = (int)x0f, yi0 = (int)y0f;
      float samp = 0.f;
#pragma unroll
      for (int dy = 0; dy < 2; ++dy) {
#pragma unroll
        for (int dx = 0; dx < 2; ++dx) {
          int xi = xi0 + dx, yi = yi0 + dy;
          float tw = (dx ? wx : 1.f - wx) * (dy ? wy : 1.f - wy);
          bool valid = (xi >= 0) && (xi < Wi) && (yi >= 0) && (yi < Hi);
          int xc = min(max(xi, 0), Wi - 1);
          int yc = min(max(yi, 0), Hi - 1);
          float vv = __bfloat162float(vb[(size_t)(st + yc * Wi + xc) * 256]);
          samp += valid ? tw * vv : 0.f;
        }
      }
      acc = fmaf(w, samp, acc);
    }
  }
  dfout[(size_t)row * 256 + tid] = acc;
}

extern "C" void kernel_launch(void* const* d_in, const int* in_sizes, int n_in,
                              void* d_out, int out_size, void* d_ws, size_t ws_size,
                              hipStream_t stream) {
  const float* tgt = (const float*)d_in[0];
  const float* memory = (const float*)d_in[1];
  const float* qpos = (const float*)d_in[2];
  const float* refp = (const float*)d_in[3];
  const float* sa_in_w = (const float*)d_in[4];
  const float* sa_in_b = (const float*)d_in[5];
  const float* sa_out_w = (const float*)d_in[6];
  const float* sa_out_b = (const float*)d_in[7];
  const float* off_w = (const float*)d_in[8];
  const float* off_b = (const float*)d_in[9];
  const float* aw_w = (const float*)d_in[10];
  const float* aw_b = (const float*)d_in[11];
  const float* val_w = (const float*)d_in[12];
  const float* val_b = (const float*)d_in[13];
  const float* co_w = (const float*)d_in[14];
  const float* co_b = (const float*)d_in[15];
  const float* l1_w = (const float*)d_in[16];
  const float* l1_b = (const float*)d_in[17];
  const float* l2_w = (const float*)d_in[18];
  const float* l2_b = (const float*)d_in[19];
  const float* ln1_s = (const float*)d_in[20];
  const float* ln1_b = (const float*)d_in[21];
  const float* ln2_s = (const float*)d_in[22];
  const float* ln2_b = (const float*)d_in[23];
  const float* ln3_s = (const float*)d_in[24];
  const float* ln3_b = (const float*)d_in[25];

  float* ws = (float*)d_ws;
  const size_t E = (size_t)BDIM * NQL * CDIM;  // 1,843,200
  // phase SA
  ushort* vt = (ushort*)(ws + E);            // bf16 [64*32][960] in [E,2E)
  float* attn_o = ws + 4 * E;                // [4E,5E)
  ushort* tmp_qk = (ushort*)(ws + 5 * E);    // bf16 [7200][512] in [5E,7E)
  ushort* tmp_v = (ushort*)(ws + 7 * E);     // bf16 [7200][256] in [7E,8E)
  float* sa_out = ws + 5 * E;                // reuse after fattn
  // phase deform
  float* offb = ws + E;                      // [E,2E)
  float* awb = ws + 2 * E;                   // [2E,2.5E)
  float* dfout = ws + 3 * E;                 // [3E,4E)
  float* co_out = ws + 4 * E;                // [4E,5E)
  // phase FFN
  ushort* hidden = (ushort*)ws;              // bf16 [7200][2048] = [0,4E)
  // persistent
  float* tgt1 = ws + 8 * E;
  float* tgt2 = ws + 9 * E;
  float* ffn_o = ws + 10 * E;
  ushort* valbf = (ushort*)(ws + 11 * E);

  const int M = BDIM * NQL;  // 7200
  const int MT = (M + 127) / 128;  // 57
  dim3 blk(256);

  // 1) q,k projections (A = tgt + qpos fused) -> bf16 [M][512]
  mgemm_kernel<false, true, false, false, true><<<dim3(4, MT), blk, 0, stream>>>(
      tgt, qpos, sa_in_w, sa_in_b, nullptr, tmp_qk, M, 512, 256);
  // 2) v projection -> bf16 [M][256]
  mgemm_kernel<false, false, false, false, true><<<dim3(2, MT), blk, 0, stream>>>(
      tgt, nullptr, sa_in_w + 512 * 256, sa_in_b + 512, nullptr, tmp_v, M, 256, 256);
  // 3) V transpose -> vt
  vt_kernel<<<dim3(15, 64), blk, 0, stream>>>(tmp_v, vt);
  // 4) MFMA flash attention
  fattn_kernel<<<dim3(15, 64), blk, 0, stream>>>(tmp_qk, vt, attn_o);
  // 5) out projection + residual(tgt)
  mgemm_kernel<false, false, false, true, false><<<dim3(2, MT), blk, 0, stream>>>(
      attn_o, nullptr, sa_out_w, sa_out_b, tgt, sa_out, M, 256, 256);
  // 6) LN1 -> tgt1
  ln_kernel<<<M, blk, 0, stream>>>(sa_out, ln1_s, ln1_b, tgt1);
  // 7) value projection -> bf16
  mgemm_kernel<false, false, false, false, true><<<dim3(2, (BDIM * LVTOT) / 128), blk, 0, stream>>>(
      memory, nullptr, val_w, val_b, nullptr, valbf, BDIM * LVTOT, 256, 256);
  // 8) offsets projection (A = tgt1 + qpos fused)
  mgemm_kernel<false, true, false, false, false><<<dim3(2, MT), blk, 0, stream>>>(
      tgt1, qpos, off_w, off_b, nullptr, offb, M, 256, 256);
  // 9) attention-weights projection (A = tgt1 + qpos fused)
  mgemm_kernel<false, true, false, false, false><<<dim3(1, MT), blk, 0, stream>>>(
      tgt1, qpos, aw_w, aw_b, nullptr, awb, M, 128, 256);
  // 10) aw softmax
  awsm_kernel<<<M, 128, 0, stream>>>(awb);
  // 11) deformable sampling
  deform_kernel<<<M, blk, 0, stream>>>((const __hip_bfloat16*)valbf, offb, awb, refp, dfout);
  // 12) co projection + residual(tgt1)
  mgemm_kernel<false, false, false, true, false><<<dim3(2, MT), blk, 0, stream>>>(
      dfout, nullptr, co_w, co_b, tgt1, co_out, M, 256, 256);
  // 13) LN2 -> tgt2
  ln_kernel<<<M, blk, 0, stream>>>(co_out, ln2_s, ln2_b, tgt2);
  // 14) FFN1 + ReLU -> bf16 hidden
  mgemm_kernel<false, false, true, false, true><<<dim3(16, MT), blk, 0, stream>>>(
      tgt2, nullptr, l1_w, l1_b, nullptr, hidden, M, 2048, 256);
  // 15) FFN2 + residual(tgt2), bf16 A
  mgemm_kernel<true, false, false, true, false><<<dim3(2, MT), blk, 0, stream>>>(
      hidden, nullptr, l2_w, l2_b, tgt2, ffn_o, M, 256, 2048);
  // 16) LN3 -> out
  ln_kernel<<<M, blk, 0, stream>>>(ffn_o, ln3_s, ln3_b, (float*)d_out);
}